// Round 1
// 551.888 us; speedup vs baseline: 1.1090x; 1.1090x over previous
//
#include <hip/hip_runtime.h>

// RGCN: hetero 2-layer GraphConv (mean aggr), MI355X.
// R7: gather ILP deepening. R6's gather was latency-bound (VALUBusy 35%,
// hbm 23% peak, occupancy 71%): unroll-2 exposed only 2 outstanding row
// loads per wave and serialized csr->xs each round (~1.2k cy/round, ~5
// rounds at mean deg 10). New gather: unroll-8 with masked tail +
// software-pipelined csr index prefetch (next 8 idx issue before waiting
// on current 8 row loads). Chain ~= L(csr) + ceil(deg/8)*L(xs).
// Everything else unchanged from R6.

#define FDIM 64
typedef unsigned short u16;
typedef unsigned int u32;
typedef __bf16 bf16x8 __attribute__((ext_vector_type(8)));
typedef float f32x4 __attribute__((ext_vector_type(4)));

__device__ __forceinline__ u16 f2bf(float x) {  // RNE
  u32 b = __builtin_bit_cast(u32, x);
  b += 0x7FFFu + ((b >> 16) & 1u);
  return (u16)(b >> 16);
}
__device__ __forceinline__ float blo(u32 p) { return __builtin_bit_cast(float, p << 16); }
__device__ __forceinline__ float bhi(u32 p) { return __builtin_bit_cast(float, p & 0xffff0000u); }

// ---- weight conversion: 12 arrays fp32 -> bf16, optional +I (skip fold) ----
struct WTab {
  const float* src[12];
  u16* dst[12];
  int rows[12];
  int addI[12];
};
__global__ __launch_bounds__(256) void k_wconv(WTab p) {
  int b = blockIdx.x;
  const float* s = p.src[b];
  u16* d = p.dst[b];
  int n = p.rows[b] * 64;
  int addI = p.addI[b];
  for (int i = threadIdx.x; i < n; i += 256) {
    float v = s[i];
    if (addI && (i >> 6) == (i & 63)) v += 1.0f;
    d[i] = f2bf(v);
  }
}

// ---- fused degree count for both edge types ----
__global__ __launch_bounds__(256) void k_count2(const int* __restrict__ dstA, int E,
                                                int* __restrict__ cntA,
                                                const int* __restrict__ dstB,
                                                int* __restrict__ cntB) {
  int i = blockIdx.x * 256 + threadIdx.x;
  if (i < E) atomicAdd(&cntA[dstA[i]], 1);
  else if (i < 2 * E) atomicAdd(&cntB[dstB[i - E]], 1);
}

__global__ __launch_bounds__(256) void k_scan1(const int* __restrict__ cnt, int n,
                                               int* __restrict__ excl,
                                               int* __restrict__ partials) {
  __shared__ int sd[256];
  int t = threadIdx.x;
  int base = blockIdx.x * 2048 + t * 8;
  int v[8]; int local = 0;
#pragma unroll
  for (int i = 0; i < 8; ++i) {
    int idx = base + i;
    int x = (idx < n) ? cnt[idx] : 0;
    v[i] = x; local += x;
  }
  sd[t] = local; __syncthreads();
  int sum = local;
  for (int off = 1; off < 256; off <<= 1) {
    int x = (t >= off) ? sd[t - off] : 0;
    __syncthreads();
    sum += x; sd[t] = sum;
    __syncthreads();
  }
  if (t == 255) partials[blockIdx.x] = sum;
  int run = sum - local;
#pragma unroll
  for (int i = 0; i < 8; ++i) {
    int idx = base + i;
    if (idx < n) excl[idx] = run;
    run += v[i];
  }
}

__global__ __launch_bounds__(256) void k_scan2(int* __restrict__ partials, int nb) {
  __shared__ int sd[256];
  int t = threadIdx.x;
  int v = (t < nb) ? partials[t] : 0;
  sd[t] = v; __syncthreads();
  int sum = v;
  for (int off = 1; off < 256; off <<= 1) {
    int x = (t >= off) ? sd[t - off] : 0;
    __syncthreads();
    sum += x; sd[t] = sum;
    __syncthreads();
  }
  if (t < nb) partials[t] = sum - v;
}

__global__ __launch_bounds__(256) void k_scan3(int* __restrict__ off,
                                               const int* __restrict__ partials, int n,
                                               int total, int* __restrict__ cursor,
                                               int shift, int* __restrict__ gcurb) {
  int idx = blockIdx.x * 256 + threadIdx.x;
  if (idx < n) {
    int v = off[idx] + partials[idx >> 11];
    off[idx] = v;
    cursor[idx] = v;
    if ((idx & ((1 << shift) - 1)) == 0) gcurb[idx >> shift] = v;
  }
  if (idx == 0) off[n] = total;
}

// ---- Pass A: bin edges into bucket-grouped (src,dst) pairs ----
#define PA_C 4096
__global__ __launch_bounds__(256) void k_binA(const int* __restrict__ src,
                                              const int* __restrict__ dst, int E,
                                              int shift, int nb,
                                              int* __restrict__ gcurb,
                                              int2* __restrict__ aux) {
  __shared__ int cnt[512];
  __shared__ int base[512];
  int t = threadIdx.x;
  int e0 = blockIdx.x * PA_C;
  int n = min(PA_C, E - e0);
  for (int b = t; b < nb; b += 256) cnt[b] = 0;
  __syncthreads();
  int ls[16], ld[16];
#pragma unroll
  for (int i = 0; i < 16; ++i) {
    int r = t + i * 256;
    if (r < n) {
      ls[i] = src[e0 + r];
      ld[i] = dst[e0 + r];
      atomicAdd(&cnt[ld[i] >> shift], 1);
    }
  }
  __syncthreads();
  for (int b = t; b < nb; b += 256) {
    int c = cnt[b];
    base[b] = c ? atomicAdd(&gcurb[b], c) : 0;
  }
  __syncthreads();
  for (int b = t; b < nb; b += 256) cnt[b] = 0;
  __syncthreads();
#pragma unroll
  for (int i = 0; i < 16; ++i) {
    int r = t + i * 256;
    if (r < n) {
      int b = ld[i] >> shift;
      int p = base[b] + atomicAdd(&cnt[b], 1);
      aux[p] = make_int2(ls[i], ld[i]);
    }
  }
}

// ---- Pass B: one block per bucket; LDS cursors + LDS-staged csr region ----
__global__ __launch_bounds__(256) void k_binB(const int2* __restrict__ aux,
                                              const int* __restrict__ off,
                                              int shift, int N,
                                              int* __restrict__ cur,
                                              int* __restrict__ csr) {
  __shared__ int stage[4096];
  __shared__ int lcur[512];
  int b = blockIdx.x;
  int d0 = b << shift;
  int d1 = min(d0 + (1 << shift), N);
  int r0 = off[d0], r1 = off[d1];
  int RS = r1 - r0;
  int t = threadIdx.x;
  if (RS <= 4096) {
    for (int i = t; i < d1 - d0; i += 256) lcur[i] = off[d0 + i] - r0;
    __syncthreads();
    for (int i = t; i < RS; i += 256) {
      int2 p = aux[r0 + i];
      int pos = atomicAdd(&lcur[p.y - d0], 1);
      stage[pos] = p.x;
    }
    __syncthreads();
    for (int i = t; i < RS; i += 256) csr[r0 + i] = stage[i];
  } else {
    for (int i = t; i < RS; i += 256) {
      int2 p = aux[r0 + i];
      int pos = atomicAdd(&cur[p.y], 1);
      csr[pos] = p.x;
    }
  }
}

// ---- dual gather-mean: wave = 2 dsts; lane = (half h, u32 chunk c) ----
// R7: unroll-8 + pipelined csr-index prefetch. Per round: 8 row loads in
// flight while next 8 csr indices are already issued. Tail edges use
// clamped duplicate indices (same-line cache hits) with a 0/1 fp mask.
struct GathSide {
  const u32* xs; const int* off; const int* csr; u32* msg; int N; int nblk;
};
__global__ __launch_bounds__(256) void k_dual_gather(GathSide A, GathSide B) {
  int bid = blockIdx.x;
  const GathSide& P = (bid < A.nblk) ? A : B;
  if (bid >= A.nblk) bid -= A.nblk;
  int lane = threadIdx.x & 63;
  int h = lane >> 5, c = lane & 31;
  int d = bid * 8 + (int)(threadIdx.x >> 6) * 2 + h;
  if (d >= P.N) return;
  int beg = P.off[d];
  int deg = P.off[d + 1] - beg;
  const u32* xs = P.xs;
  const int* csr = P.csr;
  float l0 = 0.f, h0 = 0.f, l1 = 0.f, h1 = 0.f;
  if (deg > 0) {
    int idx[8];
#pragma unroll
    for (int i = 0; i < 8; ++i) idx[i] = csr[beg + min(i, deg - 1)];
    for (int j = 0; j < deg; j += 8) {
      u32 p[8];
#pragma unroll
      for (int i = 0; i < 8; ++i) p[i] = xs[(size_t)idx[i] * 32 + c];
      int jn = j + 8;
      if (jn < deg) {  // prefetch next round's indices before waiting on p[]
#pragma unroll
        for (int i = 0; i < 8; ++i) idx[i] = csr[beg + min(jn + i, deg - 1)];
      }
#pragma unroll
      for (int i = 0; i < 8; ++i) {
        float m = (j + i < deg) ? 1.0f : 0.0f;
        if (i & 1) { l1 += blo(p[i]) * m; h1 += bhi(p[i]) * m; }
        else       { l0 += blo(p[i]) * m; h0 += bhi(p[i]) * m; }
      }
    }
  }
  float sc = 1.0f / fmaxf((float)deg, 1.0f);
  P.msg[(size_t)d * 32 + c] = (u32)f2bf((l0 + l1) * sc) | ((u32)f2bf((h0 + h1) * sc) << 16);
}

// ---- dual MFMA GEMM: Y[N,64](bf16) = act( A1 @ W1^T [+ A2 @ W2^T] + bias )
// 128-row tile, wave = 32 rows x 64 cols, direct fragment loads, no LDS.
// Layouts (m89/m91/m120): A-frag A[m=lane&15][k=q*8+j]; B-frag = rows of W;
// C/D col=lane&15, row=q*4+reg.
struct GemmSide {
  const void* A1; const u16* A2; const u16* W1; const u16* W2;
  const float* bias; u16* Y; int N; int a1fp32; int dorelu; int nblk;
};
__device__ __forceinline__ void gemm64_body(const GemmSide& P, int bid) {
  const int t = threadIdx.x;
  const int w = t >> 6, lane = t & 63;
  const int c = lane & 15, q = lane >> 4;
  const int row0 = bid * 128 + w * 32;

  bf16x8 zf;
#pragma unroll
  for (int i = 0; i < 8; ++i) zf[i] = (__bf16)0.0f;

  f32x4 acc[2][4];
#pragma unroll
  for (int ms = 0; ms < 2; ++ms)
#pragma unroll
    for (int n = 0; n < 4; ++n) acc[ms][n] = f32x4{0.f, 0.f, 0.f, 0.f};

  const int nh = (P.A2 != nullptr) ? 2 : 1;
  for (int hh = 0; hh < nh; ++hh) {
    const u16* W = hh ? P.W2 : P.W1;
    bf16x8 bfr[4][2];
#pragma unroll
    for (int n = 0; n < 4; ++n)
#pragma unroll
      for (int kc = 0; kc < 2; ++kc)
        bfr[n][kc] = *(const bf16x8*)(W + (n * 16 + c) * 64 + kc * 32 + q * 8);
    bf16x8 afr[2][2];
#pragma unroll
    for (int ms = 0; ms < 2; ++ms) {
      int row = row0 + ms * 16 + c;
      bool ok = row < P.N;
#pragma unroll
      for (int kc = 0; kc < 2; ++kc) {
        if (hh == 0 && P.a1fp32) {
          bf16x8 v = zf;
          if (ok) {
            const float* Af = (const float*)P.A1 + (size_t)row * 64 + kc * 32 + q * 8;
            float4 u0 = *(const float4*)Af;
            float4 u1 = *(const float4*)(Af + 4);
            v[0] = (__bf16)u0.x; v[1] = (__bf16)u0.y; v[2] = (__bf16)u0.z; v[3] = (__bf16)u0.w;
            v[4] = (__bf16)u1.x; v[5] = (__bf16)u1.y; v[6] = (__bf16)u1.z; v[7] = (__bf16)u1.w;
          }
          afr[ms][kc] = v;
        } else {
          const u16* Ab = (hh == 0) ? (const u16*)P.A1 : P.A2;
          afr[ms][kc] = ok ? *(const bf16x8*)(Ab + (size_t)row * 64 + kc * 32 + q * 8) : zf;
        }
      }
    }
#pragma unroll
    for (int n = 0; n < 4; ++n)
#pragma unroll
      for (int ms = 0; ms < 2; ++ms)
#pragma unroll
        for (int kc = 0; kc < 2; ++kc)
          acc[ms][n] = __builtin_amdgcn_mfma_f32_16x16x32_bf16(afr[ms][kc], bfr[n][kc],
                                                               acc[ms][n], 0, 0, 0);
  }
#pragma unroll
  for (int n = 0; n < 4; ++n) {
    float bv = P.bias[n * 16 + c];
#pragma unroll
    for (int ms = 0; ms < 2; ++ms) {
#pragma unroll
      for (int r = 0; r < 4; ++r) {
        int row = row0 + ms * 16 + q * 4 + r;
        if (row < P.N) {
          float v = acc[ms][n][r] + bv;
          if (P.dorelu) v = fmaxf(v, 0.f);
          P.Y[(size_t)row * 64 + n * 16 + c] = f2bf(v);
        }
      }
    }
  }
}
__global__ __launch_bounds__(256) void k_dual_gemm(GemmSide A, GemmSide B) {
  if ((int)blockIdx.x < A.nblk) gemm64_body(A, blockIdx.x);
  else gemm64_body(B, blockIdx.x - A.nblk);
}

// ---- dual MFMA post linear: Y[N,32](fp32) = A(bf16) @ W[32,64]^T + bias ----
struct PostSide {
  const u16* A; const u16* W; const float* bias; float* Y; int N; int nblk;
};
__device__ __forceinline__ void postlin_body(const PostSide& P, int bid) {
  const int t = threadIdx.x;
  const int w = t >> 6, lane = t & 63;
  const int c = lane & 15, q = lane >> 4;
  const int row0 = bid * 128 + w * 32;

  bf16x8 zf;
#pragma unroll
  for (int i = 0; i < 8; ++i) zf[i] = (__bf16)0.0f;

  f32x4 acc[2][2];
#pragma unroll
  for (int ms = 0; ms < 2; ++ms)
#pragma unroll
    for (int n = 0; n < 2; ++n) acc[ms][n] = f32x4{0.f, 0.f, 0.f, 0.f};

  bf16x8 bfr[2][2];
#pragma unroll
  for (int n = 0; n < 2; ++n)
#pragma unroll
    for (int kc = 0; kc < 2; ++kc)
      bfr[n][kc] = *(const bf16x8*)(P.W + (n * 16 + c) * 64 + kc * 32 + q * 8);
  bf16x8 afr[2][2];
#pragma unroll
  for (int ms = 0; ms < 2; ++ms) {
    int row = row0 + ms * 16 + c;
    bool ok = row < P.N;
#pragma unroll
    for (int kc = 0; kc < 2; ++kc)
      afr[ms][kc] = ok ? *(const bf16x8*)(P.A + (size_t)row * 64 + kc * 32 + q * 8) : zf;
  }
#pragma unroll
  for (int n = 0; n < 2; ++n)
#pragma unroll
    for (int ms = 0; ms < 2; ++ms)
#pragma unroll
      for (int kc = 0; kc < 2; ++kc)
        acc[ms][n] = __builtin_amdgcn_mfma_f32_16x16x32_bf16(afr[ms][kc], bfr[n][kc],
                                                             acc[ms][n], 0, 0, 0);
#pragma unroll
  for (int n = 0; n < 2; ++n) {
    float bv = P.bias[n * 16 + c];
#pragma unroll
    for (int ms = 0; ms < 2; ++ms) {
#pragma unroll
      for (int r = 0; r < 4; ++r) {
        int row = row0 + ms * 16 + q * 4 + r;
        if (row < P.N) P.Y[(size_t)row * 32 + n * 16 + c] = acc[ms][n][r] + bv;
      }
    }
  }
}
__global__ __launch_bounds__(256) void k_dual_postlin(PostSide A, PostSide B) {
  if ((int)blockIdx.x < A.nblk) postlin_body(A, blockIdx.x);
  else postlin_body(B, blockIdx.x - A.nblk);
}

extern "C" void kernel_launch(void* const* d_in, const int* in_sizes, int n_in,
                              void* d_out, int out_size, void* d_ws, size_t ws_size,
                              hipStream_t stream) {
  const float* x_user = (const float*)d_in[0];
  const float* x_item = (const float*)d_in[1];
  const int* ei_u2i = (const int*)d_in[2];
  const int* ei_i2u = (const int*)d_in[3];

  const int NU = in_sizes[0] / FDIM;
  const int NI = in_sizes[1] / FDIM;
  const int E = in_sizes[2] / 2;

  // ---- workspace ----
  u16* wsu = (u16*)d_ws;
  u16* h_u = wsu;   wsu += (size_t)NU * FDIM;
  u16* h_i = wsu;   wsu += (size_t)NI * FDIM;
  u16* x1_u = wsu;  wsu += (size_t)NU * FDIM;
  u16* x1_i = wsu;  wsu += (size_t)NI * FDIM;
  u16* msg_i = wsu; wsu += (size_t)NI * FDIM;
  u16* msg_u = wsu; wsu += (size_t)NU * FDIM;
  u16* wb = wsu;    wsu += 12 * 4096;
  int2* aux = (int2*)wsu;
  int* wsi = (int*)(aux + E);
  int* off_i = wsi;    wsi += NI + 1;
  int* off_u = wsi;    wsi += NU + 1;
  int* cur_i = wsi;    wsi += NI;   // contiguous with cur_u: single memset
  int* cur_u = wsi;    wsi += NU;
  int* partials = wsi; wsi += 256;
  int* gcurb_i = wsi;  wsi += 512;
  int* gcurb_u = wsi;  wsi += 512;
  int* csr_u2i = wsi;  wsi += E;
  int* csr_i2u = wsi;  wsi += E;

  const int* u2i_src = ei_u2i;
  const int* u2i_dst = ei_u2i + E;
  const int* i2u_src = ei_i2u;
  const int* i2u_dst = ei_i2u + E;

  const int gA = (E + PA_C - 1) / PA_C;
  const int tU = (NU + 127) / 128;
  const int tI = (NI + 127) / 128;
  const int bI = (NI + 2047) / 2048;
  const int bU = (NU + 2047) / 2048;
  const int gGI = (NI + 7) / 8;
  const int gGU = (NU + 7) / 8;
  const int SH_I = 8, SH_U = 9;
  const int nbI = (NI + (1 << SH_I) - 1) >> SH_I;
  const int nbU = (NU + (1 << SH_U) - 1) >> SH_U;

  // ---- weight conversion (skip folded: wroot + I) ----
  WTab tab;
  const int widx[12] = {4, 6, 8, 10, 11, 13, 14, 16, 17, 19, 20, 22};
  const int addI[12] = {0, 0, 0, 1, 0, 1, 0, 1, 0, 1, 0, 0};
  const int rows_[12] = {64, 64, 64, 64, 64, 64, 64, 64, 64, 64, 32, 32};
  for (int i = 0; i < 12; ++i) {
    tab.src[i] = (const float*)d_in[widx[i]];
    tab.dst[i] = wb + i * 4096;
    tab.rows[i] = rows_[i];
    tab.addI[i] = addI[i];
  }
  k_wconv<<<12, 256, 0, stream>>>(tab);

  // ---- pre linears (dual): fp32 x -> bf16 h ----
  {
    GemmSide a{x_user, nullptr, wb + 0 * 4096, nullptr, (const float*)d_in[5],
               h_u, NU, 1, 0, tU};
    GemmSide b{x_item, nullptr, wb + 1 * 4096, nullptr, (const float*)d_in[7],
               h_i, NI, 1, 0, tI};
    k_dual_gemm<<<tU + tI, 256, 0, stream>>>(a, b);
  }

  // ---- CSR build ----
  hipMemsetAsync(cur_i, 0, (size_t)(NI + NU) * sizeof(int), stream);
  k_count2<<<(2 * E + 255) / 256, 256, 0, stream>>>(u2i_dst, E, cur_i, i2u_dst, cur_u);
  k_scan1<<<bI, 256, 0, stream>>>(cur_i, NI, off_i, partials);
  k_scan2<<<1, 256, 0, stream>>>(partials, bI);
  k_scan3<<<(NI + 255) / 256, 256, 0, stream>>>(off_i, partials, NI, E, cur_i, SH_I, gcurb_i);
  k_binA<<<gA, 256, 0, stream>>>(u2i_src, u2i_dst, E, SH_I, nbI, gcurb_i, aux);
  k_binB<<<nbI, 256, 0, stream>>>(aux, off_i, SH_I, NI, cur_i, csr_u2i);
  k_scan1<<<bU, 256, 0, stream>>>(cur_u, NU, off_u, partials);
  k_scan2<<<1, 256, 0, stream>>>(partials, bU);
  k_scan3<<<(NU + 255) / 256, 256, 0, stream>>>(off_u, partials, NU, E, cur_u, SH_U, gcurb_u);
  k_binA<<<gA, 256, 0, stream>>>(i2u_src, i2u_dst, E, SH_U, nbU, gcurb_u, aux);
  k_binB<<<nbU, 256, 0, stream>>>(aux, off_u, SH_U, NU, cur_u, csr_i2u);

  // ---- layer 1: both gathers in one dispatch, both convs in one ----
  {
    GathSide a{(const u32*)h_u, off_i, csr_u2i, (u32*)msg_i, NI, gGI};
    GathSide b{(const u32*)h_i, off_u, csr_i2u, (u32*)msg_u, NU, gGU};
    k_dual_gather<<<gGI + gGU, 256, 0, stream>>>(a, b);
  }
  {
    GemmSide a{msg_i, h_i, wb + 2 * 4096, wb + 3 * 4096, (const float*)d_in[9],
               x1_i, NI, 0, 1, tI};
    GemmSide b{msg_u, h_u, wb + 4 * 4096, wb + 5 * 4096, (const float*)d_in[12],
               x1_u, NU, 0, 1, tU};
    k_dual_gemm<<<tI + tU, 256, 0, stream>>>(a, b);
  }

  // ---- layer 2 (outputs overwrite h_i / h_u) ----
  {
    GathSide a{(const u32*)x1_u, off_i, csr_u2i, (u32*)msg_i, NI, gGI};
    GathSide b{(const u32*)x1_i, off_u, csr_i2u, (u32*)msg_u, NU, gGU};
    k_dual_gather<<<gGI + gGU, 256, 0, stream>>>(a, b);
  }
  {
    GemmSide a{msg_i, x1_i, wb + 6 * 4096, wb + 7 * 4096, (const float*)d_in[15],
               h_i, NI, 0, 1, tI};
    GemmSide b{msg_u, x1_u, wb + 8 * 4096, wb + 9 * 4096, (const float*)d_in[18],
               h_u, NU, 0, 1, tU};
    k_dual_gemm<<<tI + tU, 256, 0, stream>>>(a, b);
  }

  // ---- post linears (dual) -> fp32 d_out = [out_u | out_i] ----
  {
    float* out = (float*)d_out;
    PostSide a{h_u, wb + 10 * 4096, (const float*)d_in[21], out, NU, tU};
    PostSide b{h_i, wb + 11 * 4096, (const float*)d_in[23], out + (size_t)NU * 32, NI, tI};
    k_dual_postlin<<<tU + tI, 256, 0, stream>>>(a, b);
  }
}

// Round 2
// 500.818 us; speedup vs baseline: 1.2220x; 1.1020x over previous
//
#include <hip/hip_runtime.h>

// RGCN: hetero 2-layer GraphConv (mean aggr), MI355X.
// R8: CSR-build redesign. R7's k_count2 was atomic-write-through-bound:
// 2M scattered device-scope atomicAdds = 62 MB WRITE_SIZE at 845 GB/s
// = 74 of its 80 us. New build: (1) k_bcount -- per-bucket LDS counts,
// per-block partials, ZERO global atomics; (2) k_bscan -- one-block
// reduce+scan of 782 buckets -> bucket offsets + binA cursors (replaces
// k_count2 + 6 scan dispatches); (3) k_binB computes per-dst counts and
// exclusive scan in LDS, writes off[] itself (global cur cursors and the
// memset are gone); (4) binA/binB are dual dispatches (aux x2).
// Gather (R7 unroll-8 pipelined) and GEMMs unchanged.

#define FDIM 64
typedef unsigned short u16;
typedef unsigned int u32;
typedef __bf16 bf16x8 __attribute__((ext_vector_type(8)));
typedef float f32x4 __attribute__((ext_vector_type(4)));

__device__ __forceinline__ u16 f2bf(float x) {  // RNE
  u32 b = __builtin_bit_cast(u32, x);
  b += 0x7FFFu + ((b >> 16) & 1u);
  return (u16)(b >> 16);
}
__device__ __forceinline__ float blo(u32 p) { return __builtin_bit_cast(float, p << 16); }
__device__ __forceinline__ float bhi(u32 p) { return __builtin_bit_cast(float, p & 0xffff0000u); }

// ---- weight conversion: 12 arrays fp32 -> bf16, optional +I (skip fold) ----
struct WTab {
  const float* src[12];
  u16* dst[12];
  int rows[12];
  int addI[12];
};
__global__ __launch_bounds__(256) void k_wconv(WTab p) {
  int b = blockIdx.x;
  const float* s = p.src[b];
  u16* d = p.dst[b];
  int n = p.rows[b] * 64;
  int addI = p.addI[b];
  for (int i = threadIdx.x; i < n; i += 256) {
    float v = s[i];
    if (addI && (i >> 6) == (i & 63)) v += 1.0f;
    d[i] = f2bf(v);
  }
}

// ---- bucket count: both edge types, LDS-aggregated, no global atomics ----
#define NB_COUNT 64
__global__ __launch_bounds__(256) void k_bcount(const int* __restrict__ dstA,
                                                const int* __restrict__ dstB, int E,
                                                int nbA, int shA, int shB, int nbTot,
                                                int* __restrict__ partial) {
  __shared__ int cnt[1024];
  int t = threadIdx.x;
  for (int i = t; i < nbTot; i += 256) cnt[i] = 0;
  __syncthreads();
  int total = 2 * E;
  for (int i = blockIdx.x * 256 + t; i < total; i += NB_COUNT * 256) {
    int b = (i < E) ? (dstA[i] >> shA) : (nbA + (dstB[i - E] >> shB));
    atomicAdd(&cnt[b], 1);
  }
  __syncthreads();
  for (int i = t; i < nbTot; i += 256) partial[blockIdx.x * nbTot + i] = cnt[i];
}

// ---- bucket scan: reduce partials + per-side exclusive scan (1 block) ----
__global__ __launch_bounds__(512) void k_bscan(const int* __restrict__ partial,
                                               int nbA, int nbB, int E,
                                               int* __restrict__ gcurbA, int* __restrict__ boffA,
                                               int* __restrict__ gcurbB, int* __restrict__ boffB) {
  __shared__ int sums[1024];
  __shared__ int sd[512];
  int t = threadIdx.x;
  int nbTot = nbA + nbB;
  for (int b = t; b < nbTot; b += 512) {
    int s = 0;
    for (int k = 0; k < NB_COUNT; ++k) s += partial[k * nbTot + b];
    sums[b] = s;
  }
  __syncthreads();
  for (int side = 0; side < 2; ++side) {
    int base = side ? nbA : 0;
    int nb = side ? nbB : nbA;
    int v = (t < nb) ? sums[base + t] : 0;
    sd[t] = v; __syncthreads();
    int sum = v;
    for (int o = 1; o < 512; o <<= 1) {
      int x = (t >= o) ? sd[t - o] : 0;
      __syncthreads();
      sum += x; sd[t] = sum;
      __syncthreads();
    }
    int excl = sum - v;
    int* gc = side ? gcurbB : gcurbA;
    int* bo = side ? boffB : boffA;
    if (t < nb) { gc[t] = excl; bo[t] = excl; }
    if (t == 0) bo[nb] = E;
    __syncthreads();
  }
}

// ---- Pass A (dual): bin edges into bucket-grouped (src,dst) pairs ----
#define PA_C 4096
struct BinASide {
  const int* src; const int* dst; int shift; int nb; int* gcurb; int2* aux;
};
__global__ __launch_bounds__(256) void k_dual_binA(BinASide A, BinASide B, int E, int gA) {
  int bid = blockIdx.x;
  const BinASide& P = (bid < gA) ? A : B;
  if (bid >= gA) bid -= gA;
  __shared__ int cnt[512];
  __shared__ int base[512];
  int t = threadIdx.x;
  int e0 = bid * PA_C;
  int n = min(PA_C, E - e0);
  int nb = P.nb, shift = P.shift;
  for (int b = t; b < nb; b += 256) cnt[b] = 0;
  __syncthreads();
  int ls[16], ld[16];
#pragma unroll
  for (int i = 0; i < 16; ++i) {
    int r = t + i * 256;
    if (r < n) {
      ls[i] = P.src[e0 + r];
      ld[i] = P.dst[e0 + r];
      atomicAdd(&cnt[ld[i] >> shift], 1);
    }
  }
  __syncthreads();
  for (int b = t; b < nb; b += 256) {
    int c = cnt[b];
    base[b] = c ? atomicAdd(&P.gcurb[b], c) : 0;
  }
  __syncthreads();
  for (int b = t; b < nb; b += 256) cnt[b] = 0;
  __syncthreads();
#pragma unroll
  for (int i = 0; i < 16; ++i) {
    int r = t + i * 256;
    if (r < n) {
      int b = ld[i] >> shift;
      int p = base[b] + atomicAdd(&cnt[b], 1);
      P.aux[p] = make_int2(ls[i], ld[i]);
    }
  }
}

// ---- Pass B (dual): per bucket -- LDS per-dst count + scan -> off[],
// then LDS-cursor scatter into staged csr region ----
struct BinBSide {
  const int2* aux; const int* boff; int shift; int N; int* off; int* csr; int nblk;
};
__global__ __launch_bounds__(256) void k_dual_binB(BinBSide A, BinBSide B) {
  __shared__ int stage[4096];
  __shared__ int lcnt[512];
  __shared__ int sd[256];
  int b = blockIdx.x;
  const BinBSide& P = (b < A.nblk) ? A : B;
  if (b >= A.nblk) b -= A.nblk;
  int t = threadIdx.x;
  int d0 = b << P.shift;
  int d1 = min(d0 + (1 << P.shift), P.N);
  int nd = d1 - d0;
  int r0 = P.boff[b], r1 = P.boff[b + 1];
  int RS = r1 - r0;
  for (int i = t; i < nd; i += 256) lcnt[i] = 0;
  __syncthreads();
  for (int i = t; i < RS; i += 256) {
    int2 p = P.aux[r0 + i];
    atomicAdd(&lcnt[p.y - d0], 1);
  }
  __syncthreads();
  // exclusive scan over nd (<=512) entries, 2 per thread
  int i0 = 2 * t, i1 = 2 * t + 1;
  int v0 = (i0 < nd) ? lcnt[i0] : 0;
  int v1 = (i1 < nd) ? lcnt[i1] : 0;
  int local = v0 + v1;
  sd[t] = local; __syncthreads();
  int sum = local;
  for (int o = 1; o < 256; o <<= 1) {
    int x = (t >= o) ? sd[t - o] : 0;
    __syncthreads();
    sum += x; sd[t] = sum;
    __syncthreads();
  }
  int run = sum - local;
  if (i0 < nd) { lcnt[i0] = run; P.off[d0 + i0] = r0 + run; }
  if (i1 < nd) { lcnt[i1] = run + v0; P.off[d0 + i1] = r0 + run + v0; }
  if (t == 0 && d1 == P.N) P.off[P.N] = r1;
  __syncthreads();
  if (RS <= 4096) {
    for (int i = t; i < RS; i += 256) {
      int2 p = P.aux[r0 + i];
      int pos = atomicAdd(&lcnt[p.y - d0], 1);
      stage[pos] = p.x;
    }
    __syncthreads();
    for (int i = t; i < RS; i += 256) P.csr[r0 + i] = stage[i];
  } else {
    for (int i = t; i < RS; i += 256) {
      int2 p = P.aux[r0 + i];
      int pos = atomicAdd(&lcnt[p.y - d0], 1);
      P.csr[r0 + pos] = p.x;
    }
  }
}

// ---- dual gather-mean: wave = 2 dsts; lane = (half h, u32 chunk c) ----
// R7: unroll-8 + pipelined csr-index prefetch. Tail edges use clamped
// duplicate indices (same-line cache hits) with a 0/1 fp mask.
struct GathSide {
  const u32* xs; const int* off; const int* csr; u32* msg; int N; int nblk;
};
__global__ __launch_bounds__(256) void k_dual_gather(GathSide A, GathSide B) {
  int bid = blockIdx.x;
  const GathSide& P = (bid < A.nblk) ? A : B;
  if (bid >= A.nblk) bid -= A.nblk;
  int lane = threadIdx.x & 63;
  int h = lane >> 5, c = lane & 31;
  int d = bid * 8 + (int)(threadIdx.x >> 6) * 2 + h;
  if (d >= P.N) return;
  int beg = P.off[d];
  int deg = P.off[d + 1] - beg;
  const u32* xs = P.xs;
  const int* csr = P.csr;
  float l0 = 0.f, h0 = 0.f, l1 = 0.f, h1 = 0.f;
  if (deg > 0) {
    int idx[8];
#pragma unroll
    for (int i = 0; i < 8; ++i) idx[i] = csr[beg + min(i, deg - 1)];
    for (int j = 0; j < deg; j += 8) {
      u32 p[8];
#pragma unroll
      for (int i = 0; i < 8; ++i) p[i] = xs[(size_t)idx[i] * 32 + c];
      int jn = j + 8;
      if (jn < deg) {  // prefetch next round's indices before waiting on p[]
#pragma unroll
        for (int i = 0; i < 8; ++i) idx[i] = csr[beg + min(jn + i, deg - 1)];
      }
#pragma unroll
      for (int i = 0; i < 8; ++i) {
        float m = (j + i < deg) ? 1.0f : 0.0f;
        if (i & 1) { l1 += blo(p[i]) * m; h1 += bhi(p[i]) * m; }
        else       { l0 += blo(p[i]) * m; h0 += bhi(p[i]) * m; }
      }
    }
  }
  float sc = 1.0f / fmaxf((float)deg, 1.0f);
  P.msg[(size_t)d * 32 + c] = (u32)f2bf((l0 + l1) * sc) | ((u32)f2bf((h0 + h1) * sc) << 16);
}

// ---- dual MFMA GEMM: Y[N,64](bf16) = act( A1 @ W1^T [+ A2 @ W2^T] + bias )
// 128-row tile, wave = 32 rows x 64 cols, direct fragment loads, no LDS.
// Layouts (m89/m91/m120): A-frag A[m=lane&15][k=q*8+j]; B-frag = rows of W;
// C/D col=lane&15, row=q*4+reg.
struct GemmSide {
  const void* A1; const u16* A2; const u16* W1; const u16* W2;
  const float* bias; u16* Y; int N; int a1fp32; int dorelu; int nblk;
};
__device__ __forceinline__ void gemm64_body(const GemmSide& P, int bid) {
  const int t = threadIdx.x;
  const int w = t >> 6, lane = t & 63;
  const int c = lane & 15, q = lane >> 4;
  const int row0 = bid * 128 + w * 32;

  bf16x8 zf;
#pragma unroll
  for (int i = 0; i < 8; ++i) zf[i] = (__bf16)0.0f;

  f32x4 acc[2][4];
#pragma unroll
  for (int ms = 0; ms < 2; ++ms)
#pragma unroll
    for (int n = 0; n < 4; ++n) acc[ms][n] = f32x4{0.f, 0.f, 0.f, 0.f};

  const int nh = (P.A2 != nullptr) ? 2 : 1;
  for (int hh = 0; hh < nh; ++hh) {
    const u16* W = hh ? P.W2 : P.W1;
    bf16x8 bfr[4][2];
#pragma unroll
    for (int n = 0; n < 4; ++n)
#pragma unroll
      for (int kc = 0; kc < 2; ++kc)
        bfr[n][kc] = *(const bf16x8*)(W + (n * 16 + c) * 64 + kc * 32 + q * 8);
    bf16x8 afr[2][2];
#pragma unroll
    for (int ms = 0; ms < 2; ++ms) {
      int row = row0 + ms * 16 + c;
      bool ok = row < P.N;
#pragma unroll
      for (int kc = 0; kc < 2; ++kc) {
        if (hh == 0 && P.a1fp32) {
          bf16x8 v = zf;
          if (ok) {
            const float* Af = (const float*)P.A1 + (size_t)row * 64 + kc * 32 + q * 8;
            float4 u0 = *(const float4*)Af;
            float4 u1 = *(const float4*)(Af + 4);
            v[0] = (__bf16)u0.x; v[1] = (__bf16)u0.y; v[2] = (__bf16)u0.z; v[3] = (__bf16)u0.w;
            v[4] = (__bf16)u1.x; v[5] = (__bf16)u1.y; v[6] = (__bf16)u1.z; v[7] = (__bf16)u1.w;
          }
          afr[ms][kc] = v;
        } else {
          const u16* Ab = (hh == 0) ? (const u16*)P.A1 : P.A2;
          afr[ms][kc] = ok ? *(const bf16x8*)(Ab + (size_t)row * 64 + kc * 32 + q * 8) : zf;
        }
      }
    }
#pragma unroll
    for (int n = 0; n < 4; ++n)
#pragma unroll
      for (int ms = 0; ms < 2; ++ms)
#pragma unroll
        for (int kc = 0; kc < 2; ++kc)
          acc[ms][n] = __builtin_amdgcn_mfma_f32_16x16x32_bf16(afr[ms][kc], bfr[n][kc],
                                                               acc[ms][n], 0, 0, 0);
  }
#pragma unroll
  for (int n = 0; n < 4; ++n) {
    float bv = P.bias[n * 16 + c];
#pragma unroll
    for (int ms = 0; ms < 2; ++ms) {
#pragma unroll
      for (int r = 0; r < 4; ++r) {
        int row = row0 + ms * 16 + q * 4 + r;
        if (row < P.N) {
          float v = acc[ms][n][r] + bv;
          if (P.dorelu) v = fmaxf(v, 0.f);
          P.Y[(size_t)row * 64 + n * 16 + c] = f2bf(v);
        }
      }
    }
  }
}
__global__ __launch_bounds__(256) void k_dual_gemm(GemmSide A, GemmSide B) {
  if ((int)blockIdx.x < A.nblk) gemm64_body(A, blockIdx.x);
  else gemm64_body(B, blockIdx.x - A.nblk);
}

// ---- dual MFMA post linear: Y[N,32](fp32) = A(bf16) @ W[32,64]^T + bias ----
struct PostSide {
  const u16* A; const u16* W; const float* bias; float* Y; int N; int nblk;
};
__device__ __forceinline__ void postlin_body(const PostSide& P, int bid) {
  const int t = threadIdx.x;
  const int w = t >> 6, lane = t & 63;
  const int c = lane & 15, q = lane >> 4;
  const int row0 = bid * 128 + w * 32;

  bf16x8 zf;
#pragma unroll
  for (int i = 0; i < 8; ++i) zf[i] = (__bf16)0.0f;

  f32x4 acc[2][2];
#pragma unroll
  for (int ms = 0; ms < 2; ++ms)
#pragma unroll
    for (int n = 0; n < 2; ++n) acc[ms][n] = f32x4{0.f, 0.f, 0.f, 0.f};

  bf16x8 bfr[2][2];
#pragma unroll
  for (int n = 0; n < 2; ++n)
#pragma unroll
    for (int kc = 0; kc < 2; ++kc)
      bfr[n][kc] = *(const bf16x8*)(P.W + (n * 16 + c) * 64 + kc * 32 + q * 8);
  bf16x8 afr[2][2];
#pragma unroll
  for (int ms = 0; ms < 2; ++ms) {
    int row = row0 + ms * 16 + c;
    bool ok = row < P.N;
#pragma unroll
    for (int kc = 0; kc < 2; ++kc)
      afr[ms][kc] = ok ? *(const bf16x8*)(P.A + (size_t)row * 64 + kc * 32 + q * 8) : zf;
  }
#pragma unroll
  for (int n = 0; n < 2; ++n)
#pragma unroll
    for (int ms = 0; ms < 2; ++ms)
#pragma unroll
      for (int kc = 0; kc < 2; ++kc)
        acc[ms][n] = __builtin_amdgcn_mfma_f32_16x16x32_bf16(afr[ms][kc], bfr[n][kc],
                                                             acc[ms][n], 0, 0, 0);
#pragma unroll
  for (int n = 0; n < 2; ++n) {
    float bv = P.bias[n * 16 + c];
#pragma unroll
    for (int ms = 0; ms < 2; ++ms) {
#pragma unroll
      for (int r = 0; r < 4; ++r) {
        int row = row0 + ms * 16 + q * 4 + r;
        if (row < P.N) P.Y[(size_t)row * 32 + n * 16 + c] = acc[ms][n][r] + bv;
      }
    }
  }
}
__global__ __launch_bounds__(256) void k_dual_postlin(PostSide A, PostSide B) {
  if ((int)blockIdx.x < A.nblk) postlin_body(A, blockIdx.x);
  else postlin_body(B, blockIdx.x - A.nblk);
}

extern "C" void kernel_launch(void* const* d_in, const int* in_sizes, int n_in,
                              void* d_out, int out_size, void* d_ws, size_t ws_size,
                              hipStream_t stream) {
  const float* x_user = (const float*)d_in[0];
  const float* x_item = (const float*)d_in[1];
  const int* ei_u2i = (const int*)d_in[2];
  const int* ei_i2u = (const int*)d_in[3];

  const int NU = in_sizes[0] / FDIM;
  const int NI = in_sizes[1] / FDIM;
  const int E = in_sizes[2] / 2;

  const int SH_I = 8, SH_U = 9;
  const int nbI = (NI + (1 << SH_I) - 1) >> SH_I;
  const int nbU = (NU + (1 << SH_U) - 1) >> SH_U;
  const int nbTot = nbI + nbU;

  // ---- workspace ----
  u16* wsu = (u16*)d_ws;
  u16* h_u = wsu;   wsu += (size_t)NU * FDIM;
  u16* h_i = wsu;   wsu += (size_t)NI * FDIM;
  u16* x1_u = wsu;  wsu += (size_t)NU * FDIM;
  u16* x1_i = wsu;  wsu += (size_t)NI * FDIM;
  u16* msg_i = wsu; wsu += (size_t)NI * FDIM;
  u16* msg_u = wsu; wsu += (size_t)NU * FDIM;
  u16* wb = wsu;    wsu += 12 * 4096;
  int2* aux_i = (int2*)wsu;
  int2* aux_u = aux_i + E;
  int* wsi = (int*)(aux_u + E);
  int* off_i = wsi;    wsi += NI + 1;
  int* off_u = wsi;    wsi += NU + 1;
  int* boff_i = wsi;   wsi += nbI + 1;
  int* boff_u = wsi;   wsi += nbU + 1;
  int* gcurb_i = wsi;  wsi += 512;
  int* gcurb_u = wsi;  wsi += 512;
  int* bpart = wsi;    wsi += NB_COUNT * nbTot;
  int* csr_u2i = wsi;  wsi += E;
  int* csr_i2u = wsi;  wsi += E;

  const int* u2i_src = ei_u2i;
  const int* u2i_dst = ei_u2i + E;
  const int* i2u_src = ei_i2u;
  const int* i2u_dst = ei_i2u + E;

  const int gA = (E + PA_C - 1) / PA_C;
  const int tU = (NU + 127) / 128;
  const int tI = (NI + 127) / 128;
  const int gGI = (NI + 7) / 8;
  const int gGU = (NU + 7) / 8;

  // ---- weight conversion (skip folded: wroot + I) ----
  WTab tab;
  const int widx[12] = {4, 6, 8, 10, 11, 13, 14, 16, 17, 19, 20, 22};
  const int addI[12] = {0, 0, 0, 1, 0, 1, 0, 1, 0, 1, 0, 0};
  const int rows_[12] = {64, 64, 64, 64, 64, 64, 64, 64, 64, 64, 32, 32};
  for (int i = 0; i < 12; ++i) {
    tab.src[i] = (const float*)d_in[widx[i]];
    tab.dst[i] = wb + i * 4096;
    tab.rows[i] = rows_[i];
    tab.addI[i] = addI[i];
  }
  k_wconv<<<12, 256, 0, stream>>>(tab);

  // ---- pre linears (dual): fp32 x -> bf16 h ----
  {
    GemmSide a{x_user, nullptr, wb + 0 * 4096, nullptr, (const float*)d_in[5],
               h_u, NU, 1, 0, tU};
    GemmSide b{x_item, nullptr, wb + 1 * 4096, nullptr, (const float*)d_in[7],
               h_i, NI, 1, 0, tI};
    k_dual_gemm<<<tU + tI, 256, 0, stream>>>(a, b);
  }

  // ---- CSR build (atomic-free counts) ----
  k_bcount<<<NB_COUNT, 256, 0, stream>>>(u2i_dst, i2u_dst, E, nbI, SH_I, SH_U, nbTot, bpart);
  k_bscan<<<1, 512, 0, stream>>>(bpart, nbI, nbU, E, gcurb_i, boff_i, gcurb_u, boff_u);
  {
    BinASide a{u2i_src, u2i_dst, SH_I, nbI, gcurb_i, aux_i};
    BinASide b{i2u_src, i2u_dst, SH_U, nbU, gcurb_u, aux_u};
    k_dual_binA<<<2 * gA, 256, 0, stream>>>(a, b, E, gA);
  }
  {
    BinBSide a{aux_i, boff_i, SH_I, NI, off_i, csr_u2i, nbI};
    BinBSide b{aux_u, boff_u, SH_U, NU, off_u, csr_i2u, nbU};
    k_dual_binB<<<nbI + nbU, 256, 0, stream>>>(a, b);
  }

  // ---- layer 1: both gathers in one dispatch, both convs in one ----
  {
    GathSide a{(const u32*)h_u, off_i, csr_u2i, (u32*)msg_i, NI, gGI};
    GathSide b{(const u32*)h_i, off_u, csr_i2u, (u32*)msg_u, NU, gGU};
    k_dual_gather<<<gGI + gGU, 256, 0, stream>>>(a, b);
  }
  {
    GemmSide a{msg_i, h_i, wb + 2 * 4096, wb + 3 * 4096, (const float*)d_in[9],
               x1_i, NI, 0, 1, tI};
    GemmSide b{msg_u, h_u, wb + 4 * 4096, wb + 5 * 4096, (const float*)d_in[12],
               x1_u, NU, 0, 1, tU};
    k_dual_gemm<<<tI + tU, 256, 0, stream>>>(a, b);
  }

  // ---- layer 2 (outputs overwrite h_i / h_u) ----
  {
    GathSide a{(const u32*)x1_u, off_i, csr_u2i, (u32*)msg_i, NI, gGI};
    GathSide b{(const u32*)x1_i, off_u, csr_i2u, (u32*)msg_u, NU, gGU};
    k_dual_gather<<<gGI + gGU, 256, 0, stream>>>(a, b);
  }
  {
    GemmSide a{msg_i, x1_i, wb + 6 * 4096, wb + 7 * 4096, (const float*)d_in[15],
               h_i, NI, 0, 1, tI};
    GemmSide b{msg_u, x1_u, wb + 8 * 4096, wb + 9 * 4096, (const float*)d_in[18],
               h_u, NU, 0, 1, tU};
    k_dual_gemm<<<tI + tU, 256, 0, stream>>>(a, b);
  }

  // ---- post linears (dual) -> fp32 d_out = [out_u | out_i] ----
  {
    float* out = (float*)d_out;
    PostSide a{h_u, wb + 10 * 4096, (const float*)d_in[21], out, NU, tU};
    PostSide b{h_i, wb + 11 * 4096, (const float*)d_in[23], out + (size_t)NU * 32, NI, tI};
    k_dual_postlin<<<tU + tI, 256, 0, stream>>>(a, b);
  }
}

// Round 3
// 440.858 us; speedup vs baseline: 1.3882x; 1.1360x over previous
//
#include <hip/hip_runtime.h>

// RGCN: hetero 2-layer GraphConv (mean aggr), MI355X.
// R9: kill the pre-count. R8's k_bcount ran 64 blocks on 256 CUs
// (Occupancy 2.5%, VALU 0.6%, HBM 0.9%) -- 60 us of pure latency
// serialization for 1.3 us of bandwidth work. New: slotted aux. Each
// bucket gets a fixed S=3072-slot region (expected load 2560 +- 51,
// overflow ~20 sigma improbable); binA cursors init to b*S with no
// prior counts; a 1-block scan of (gcurb[b]-b*S) after binA yields
// compact CSR bases for binB. k_bcount + bpart deleted.
// Gather (R7 unroll-8 pipelined), GEMMs, binA/binB cores unchanged.

#define FDIM 64
typedef unsigned short u16;
typedef unsigned int u32;
typedef __bf16 bf16x8 __attribute__((ext_vector_type(8)));
typedef float f32x4 __attribute__((ext_vector_type(4)));

#define SLOT_S 3072

__device__ __forceinline__ u16 f2bf(float x) {  // RNE
  u32 b = __builtin_bit_cast(u32, x);
  b += 0x7FFFu + ((b >> 16) & 1u);
  return (u16)(b >> 16);
}
__device__ __forceinline__ float blo(u32 p) { return __builtin_bit_cast(float, p << 16); }
__device__ __forceinline__ float bhi(u32 p) { return __builtin_bit_cast(float, p & 0xffff0000u); }

// ---- weight conversion: 12 arrays fp32 -> bf16, optional +I (skip fold) ----
struct WTab {
  const float* src[12];
  u16* dst[12];
  int rows[12];
  int addI[12];
};
__global__ __launch_bounds__(256) void k_wconv(WTab p) {
  int b = blockIdx.x;
  const float* s = p.src[b];
  u16* d = p.dst[b];
  int n = p.rows[b] * 64;
  int addI = p.addI[b];
  for (int i = threadIdx.x; i < n; i += 256) {
    float v = s[i];
    if (addI && (i >> 6) == (i & 63)) v += 1.0f;
    d[i] = f2bf(v);
  }
}

// ---- init binA cursors to slot bases (no pre-count needed) ----
__global__ __launch_bounds__(256) void k_init_gcurb(int* __restrict__ gA, int nA,
                                                    int* __restrict__ gB, int nB) {
  int i = blockIdx.x * 256 + threadIdx.x;
  if (i < nA) gA[i] = i * SLOT_S;
  else if (i < nA + nB) gB[i - nA] = (i - nA) * SLOT_S;
}

// ---- bucket scan (post-binA): counts = gcurb[b]-b*S, exclusive scan ----
__global__ __launch_bounds__(512) void k_bscan2(const int* __restrict__ gcA, int nbA,
                                                const int* __restrict__ gcB, int nbB,
                                                int* __restrict__ boffA,
                                                int* __restrict__ boffB) {
  __shared__ int sd[512];
  int t = threadIdx.x;
  for (int side = 0; side < 2; ++side) {
    const int* gc = side ? gcB : gcA;
    int nb = side ? nbB : nbA;
    int v = (t < nb) ? gc[t] - t * SLOT_S : 0;
    sd[t] = v; __syncthreads();
    int sum = v;
    for (int o = 1; o < 512; o <<= 1) {
      int x = (t >= o) ? sd[t - o] : 0;
      __syncthreads();
      sum += x; sd[t] = sum;
      __syncthreads();
    }
    int* bo = side ? boffB : boffA;
    if (t < nb) bo[t] = sum - v;
    if (t == nb - 1) bo[nb] = sum;
    __syncthreads();
  }
}

// ---- Pass A (dual): bin edges into per-bucket slot regions ----
#define PA_C 4096
struct BinASide {
  const int* src; const int* dst; int shift; int nb; int* gcurb; int2* aux;
};
__global__ __launch_bounds__(256) void k_dual_binA(BinASide A, BinASide B, int E, int gA) {
  int bid = blockIdx.x;
  const BinASide& P = (bid < gA) ? A : B;
  if (bid >= gA) bid -= gA;
  __shared__ int cnt[512];
  __shared__ int base[512];
  int t = threadIdx.x;
  int e0 = bid * PA_C;
  int n = min(PA_C, E - e0);
  int nb = P.nb, shift = P.shift;
  for (int b = t; b < nb; b += 256) cnt[b] = 0;
  __syncthreads();
  int ls[16], ld[16];
#pragma unroll
  for (int i = 0; i < 16; ++i) {
    int r = t + i * 256;
    if (r < n) {
      ls[i] = P.src[e0 + r];
      ld[i] = P.dst[e0 + r];
      atomicAdd(&cnt[ld[i] >> shift], 1);
    }
  }
  __syncthreads();
  for (int b = t; b < nb; b += 256) {
    int c = cnt[b];
    base[b] = c ? atomicAdd(&P.gcurb[b], c) : 0;
  }
  __syncthreads();
  for (int b = t; b < nb; b += 256) cnt[b] = 0;
  __syncthreads();
#pragma unroll
  for (int i = 0; i < 16; ++i) {
    int r = t + i * 256;
    if (r < n) {
      int b = ld[i] >> shift;
      int p = base[b] + atomicAdd(&cnt[b], 1);
      P.aux[p] = make_int2(ls[i], ld[i]);
    }
  }
}

// ---- Pass B (dual): per bucket -- LDS per-dst count + scan -> off[],
// then LDS-cursor scatter from slotted aux into compact csr ----
struct BinBSide {
  const int2* aux; const int* gcurb; const int* boff; int shift; int N;
  int* off; int* csr; int nblk;
};
__global__ __launch_bounds__(256) void k_dual_binB(BinBSide A, BinBSide B) {
  __shared__ int stage[4096];
  __shared__ int lcnt[512];
  __shared__ int sd[256];
  int b = blockIdx.x;
  const BinBSide& P = (b < A.nblk) ? A : B;
  if (b >= A.nblk) b -= A.nblk;
  int t = threadIdx.x;
  int d0 = b << P.shift;
  int d1 = min(d0 + (1 << P.shift), P.N);
  int nd = d1 - d0;
  size_t a0 = (size_t)b * SLOT_S;
  int r0 = P.boff[b];
  int RS = P.gcurb[b] - b * SLOT_S;
  for (int i = t; i < nd; i += 256) lcnt[i] = 0;
  __syncthreads();
  for (int i = t; i < RS; i += 256) {
    int2 p = P.aux[a0 + i];
    atomicAdd(&lcnt[p.y - d0], 1);
  }
  __syncthreads();
  // exclusive scan over nd (<=512) entries, 2 per thread
  int i0 = 2 * t, i1 = 2 * t + 1;
  int v0 = (i0 < nd) ? lcnt[i0] : 0;
  int v1 = (i1 < nd) ? lcnt[i1] : 0;
  int local = v0 + v1;
  sd[t] = local; __syncthreads();
  int sum = local;
  for (int o = 1; o < 256; o <<= 1) {
    int x = (t >= o) ? sd[t - o] : 0;
    __syncthreads();
    sum += x; sd[t] = sum;
    __syncthreads();
  }
  int run = sum - local;
  if (i0 < nd) { lcnt[i0] = run; P.off[d0 + i0] = r0 + run; }
  if (i1 < nd) { lcnt[i1] = run + v0; P.off[d0 + i1] = r0 + run + v0; }
  if (t == 0 && d1 == P.N) P.off[P.N] = r0 + RS;
  __syncthreads();
  if (RS <= 4096) {
    for (int i = t; i < RS; i += 256) {
      int2 p = P.aux[a0 + i];
      int pos = atomicAdd(&lcnt[p.y - d0], 1);
      stage[pos] = p.x;
    }
    __syncthreads();
    for (int i = t; i < RS; i += 256) P.csr[r0 + i] = stage[i];
  } else {
    for (int i = t; i < RS; i += 256) {
      int2 p = P.aux[a0 + i];
      int pos = atomicAdd(&lcnt[p.y - d0], 1);
      P.csr[r0 + pos] = p.x;
    }
  }
}

// ---- dual gather-mean: wave = 2 dsts; lane = (half h, u32 chunk c) ----
// R7: unroll-8 + pipelined csr-index prefetch. Tail edges use clamped
// duplicate indices (same-line cache hits) with a 0/1 fp mask.
struct GathSide {
  const u32* xs; const int* off; const int* csr; u32* msg; int N; int nblk;
};
__global__ __launch_bounds__(256) void k_dual_gather(GathSide A, GathSide B) {
  int bid = blockIdx.x;
  const GathSide& P = (bid < A.nblk) ? A : B;
  if (bid >= A.nblk) bid -= A.nblk;
  int lane = threadIdx.x & 63;
  int h = lane >> 5, c = lane & 31;
  int d = bid * 8 + (int)(threadIdx.x >> 6) * 2 + h;
  if (d >= P.N) return;
  int beg = P.off[d];
  int deg = P.off[d + 1] - beg;
  const u32* xs = P.xs;
  const int* csr = P.csr;
  float l0 = 0.f, h0 = 0.f, l1 = 0.f, h1 = 0.f;
  if (deg > 0) {
    int idx[8];
#pragma unroll
    for (int i = 0; i < 8; ++i) idx[i] = csr[beg + min(i, deg - 1)];
    for (int j = 0; j < deg; j += 8) {
      u32 p[8];
#pragma unroll
      for (int i = 0; i < 8; ++i) p[i] = xs[(size_t)idx[i] * 32 + c];
      int jn = j + 8;
      if (jn < deg) {  // prefetch next round's indices before waiting on p[]
#pragma unroll
        for (int i = 0; i < 8; ++i) idx[i] = csr[beg + min(jn + i, deg - 1)];
      }
#pragma unroll
      for (int i = 0; i < 8; ++i) {
        float m = (j + i < deg) ? 1.0f : 0.0f;
        if (i & 1) { l1 += blo(p[i]) * m; h1 += bhi(p[i]) * m; }
        else       { l0 += blo(p[i]) * m; h0 += bhi(p[i]) * m; }
      }
    }
  }
  float sc = 1.0f / fmaxf((float)deg, 1.0f);
  P.msg[(size_t)d * 32 + c] = (u32)f2bf((l0 + l1) * sc) | ((u32)f2bf((h0 + h1) * sc) << 16);
}

// ---- dual MFMA GEMM: Y[N,64](bf16) = act( A1 @ W1^T [+ A2 @ W2^T] + bias )
// 128-row tile, wave = 32 rows x 64 cols, direct fragment loads, no LDS.
// Layouts (m89/m91/m120): A-frag A[m=lane&15][k=q*8+j]; B-frag = rows of W;
// C/D col=lane&15, row=q*4+reg.
struct GemmSide {
  const void* A1; const u16* A2; const u16* W1; const u16* W2;
  const float* bias; u16* Y; int N; int a1fp32; int dorelu; int nblk;
};
__device__ __forceinline__ void gemm64_body(const GemmSide& P, int bid) {
  const int t = threadIdx.x;
  const int w = t >> 6, lane = t & 63;
  const int c = lane & 15, q = lane >> 4;
  const int row0 = bid * 128 + w * 32;

  bf16x8 zf;
#pragma unroll
  for (int i = 0; i < 8; ++i) zf[i] = (__bf16)0.0f;

  f32x4 acc[2][4];
#pragma unroll
  for (int ms = 0; ms < 2; ++ms)
#pragma unroll
    for (int n = 0; n < 4; ++n) acc[ms][n] = f32x4{0.f, 0.f, 0.f, 0.f};

  const int nh = (P.A2 != nullptr) ? 2 : 1;
  for (int hh = 0; hh < nh; ++hh) {
    const u16* W = hh ? P.W2 : P.W1;
    bf16x8 bfr[4][2];
#pragma unroll
    for (int n = 0; n < 4; ++n)
#pragma unroll
      for (int kc = 0; kc < 2; ++kc)
        bfr[n][kc] = *(const bf16x8*)(W + (n * 16 + c) * 64 + kc * 32 + q * 8);
    bf16x8 afr[2][2];
#pragma unroll
    for (int ms = 0; ms < 2; ++ms) {
      int row = row0 + ms * 16 + c;
      bool ok = row < P.N;
#pragma unroll
      for (int kc = 0; kc < 2; ++kc) {
        if (hh == 0 && P.a1fp32) {
          bf16x8 v = zf;
          if (ok) {
            const float* Af = (const float*)P.A1 + (size_t)row * 64 + kc * 32 + q * 8;
            float4 u0 = *(const float4*)Af;
            float4 u1 = *(const float4*)(Af + 4);
            v[0] = (__bf16)u0.x; v[1] = (__bf16)u0.y; v[2] = (__bf16)u0.z; v[3] = (__bf16)u0.w;
            v[4] = (__bf16)u1.x; v[5] = (__bf16)u1.y; v[6] = (__bf16)u1.z; v[7] = (__bf16)u1.w;
          }
          afr[ms][kc] = v;
        } else {
          const u16* Ab = (hh == 0) ? (const u16*)P.A1 : P.A2;
          afr[ms][kc] = ok ? *(const bf16x8*)(Ab + (size_t)row * 64 + kc * 32 + q * 8) : zf;
        }
      }
    }
#pragma unroll
    for (int n = 0; n < 4; ++n)
#pragma unroll
      for (int ms = 0; ms < 2; ++ms)
#pragma unroll
        for (int kc = 0; kc < 2; ++kc)
          acc[ms][n] = __builtin_amdgcn_mfma_f32_16x16x32_bf16(afr[ms][kc], bfr[n][kc],
                                                               acc[ms][n], 0, 0, 0);
  }
#pragma unroll
  for (int n = 0; n < 4; ++n) {
    float bv = P.bias[n * 16 + c];
#pragma unroll
    for (int ms = 0; ms < 2; ++ms) {
#pragma unroll
      for (int r = 0; r < 4; ++r) {
        int row = row0 + ms * 16 + q * 4 + r;
        if (row < P.N) {
          float v = acc[ms][n][r] + bv;
          if (P.dorelu) v = fmaxf(v, 0.f);
          P.Y[(size_t)row * 64 + n * 16 + c] = f2bf(v);
        }
      }
    }
  }
}
__global__ __launch_bounds__(256) void k_dual_gemm(GemmSide A, GemmSide B) {
  if ((int)blockIdx.x < A.nblk) gemm64_body(A, blockIdx.x);
  else gemm64_body(B, blockIdx.x - A.nblk);
}

// ---- dual MFMA post linear: Y[N,32](fp32) = A(bf16) @ W[32,64]^T + bias ----
struct PostSide {
  const u16* A; const u16* W; const float* bias; float* Y; int N; int nblk;
};
__device__ __forceinline__ void postlin_body(const PostSide& P, int bid) {
  const int t = threadIdx.x;
  const int w = t >> 6, lane = t & 63;
  const int c = lane & 15, q = lane >> 4;
  const int row0 = bid * 128 + w * 32;

  bf16x8 zf;
#pragma unroll
  for (int i = 0; i < 8; ++i) zf[i] = (__bf16)0.0f;

  f32x4 acc[2][2];
#pragma unroll
  for (int ms = 0; ms < 2; ++ms)
#pragma unroll
    for (int n = 0; n < 2; ++n) acc[ms][n] = f32x4{0.f, 0.f, 0.f, 0.f};

  bf16x8 bfr[2][2];
#pragma unroll
  for (int n = 0; n < 2; ++n)
#pragma unroll
    for (int kc = 0; kc < 2; ++kc)
      bfr[n][kc] = *(const bf16x8*)(P.W + (n * 16 + c) * 64 + kc * 32 + q * 8);
  bf16x8 afr[2][2];
#pragma unroll
  for (int ms = 0; ms < 2; ++ms) {
    int row = row0 + ms * 16 + c;
    bool ok = row < P.N;
#pragma unroll
    for (int kc = 0; kc < 2; ++kc)
      afr[ms][kc] = ok ? *(const bf16x8*)(P.A + (size_t)row * 64 + kc * 32 + q * 8) : zf;
  }
#pragma unroll
  for (int n = 0; n < 2; ++n)
#pragma unroll
    for (int ms = 0; ms < 2; ++ms)
#pragma unroll
      for (int kc = 0; kc < 2; ++kc)
        acc[ms][n] = __builtin_amdgcn_mfma_f32_16x16x32_bf16(afr[ms][kc], bfr[n][kc],
                                                             acc[ms][n], 0, 0, 0);
#pragma unroll
  for (int n = 0; n < 2; ++n) {
    float bv = P.bias[n * 16 + c];
#pragma unroll
    for (int ms = 0; ms < 2; ++ms) {
#pragma unroll
      for (int r = 0; r < 4; ++r) {
        int row = row0 + ms * 16 + q * 4 + r;
        if (row < P.N) P.Y[(size_t)row * 32 + n * 16 + c] = acc[ms][n][r] + bv;
      }
    }
  }
}
__global__ __launch_bounds__(256) void k_dual_postlin(PostSide A, PostSide B) {
  if ((int)blockIdx.x < A.nblk) postlin_body(A, blockIdx.x);
  else postlin_body(B, blockIdx.x - A.nblk);
}

extern "C" void kernel_launch(void* const* d_in, const int* in_sizes, int n_in,
                              void* d_out, int out_size, void* d_ws, size_t ws_size,
                              hipStream_t stream) {
  const float* x_user = (const float*)d_in[0];
  const float* x_item = (const float*)d_in[1];
  const int* ei_u2i = (const int*)d_in[2];
  const int* ei_i2u = (const int*)d_in[3];

  const int NU = in_sizes[0] / FDIM;
  const int NI = in_sizes[1] / FDIM;
  const int E = in_sizes[2] / 2;

  const int SH_I = 8, SH_U = 9;
  const int nbI = (NI + (1 << SH_I) - 1) >> SH_I;
  const int nbU = (NU + (1 << SH_U) - 1) >> SH_U;

  // ---- workspace ----
  u16* wsu = (u16*)d_ws;
  u16* h_u = wsu;   wsu += (size_t)NU * FDIM;
  u16* h_i = wsu;   wsu += (size_t)NI * FDIM;
  u16* x1_u = wsu;  wsu += (size_t)NU * FDIM;
  u16* x1_i = wsu;  wsu += (size_t)NI * FDIM;
  u16* msg_i = wsu; wsu += (size_t)NI * FDIM;
  u16* msg_u = wsu; wsu += (size_t)NU * FDIM;
  u16* wb = wsu;    wsu += 12 * 4096;
  int2* aux_i = (int2*)wsu;
  int2* aux_u = aux_i + (size_t)nbI * SLOT_S;
  int* wsi = (int*)(aux_u + (size_t)nbU * SLOT_S);
  int* off_i = wsi;    wsi += NI + 1;
  int* off_u = wsi;    wsi += NU + 1;
  int* boff_i = wsi;   wsi += nbI + 1;
  int* boff_u = wsi;   wsi += nbU + 1;
  int* gcurb_i = wsi;  wsi += 512;
  int* gcurb_u = wsi;  wsi += 512;
  int* csr_u2i = wsi;  wsi += E;
  int* csr_i2u = wsi;  wsi += E;

  const int* u2i_src = ei_u2i;
  const int* u2i_dst = ei_u2i + E;
  const int* i2u_src = ei_i2u;
  const int* i2u_dst = ei_i2u + E;

  const int gA = (E + PA_C - 1) / PA_C;
  const int tU = (NU + 127) / 128;
  const int tI = (NI + 127) / 128;
  const int gGI = (NI + 7) / 8;
  const int gGU = (NU + 7) / 8;

  // ---- weight conversion (skip folded: wroot + I) ----
  WTab tab;
  const int widx[12] = {4, 6, 8, 10, 11, 13, 14, 16, 17, 19, 20, 22};
  const int addI[12] = {0, 0, 0, 1, 0, 1, 0, 1, 0, 1, 0, 0};
  const int rows_[12] = {64, 64, 64, 64, 64, 64, 64, 64, 64, 64, 32, 32};
  for (int i = 0; i < 12; ++i) {
    tab.src[i] = (const float*)d_in[widx[i]];
    tab.dst[i] = wb + i * 4096;
    tab.rows[i] = rows_[i];
    tab.addI[i] = addI[i];
  }
  k_wconv<<<12, 256, 0, stream>>>(tab);
  k_init_gcurb<<<(nbI + nbU + 255) / 256, 256, 0, stream>>>(gcurb_i, nbI, gcurb_u, nbU);

  // ---- pre linears (dual): fp32 x -> bf16 h ----
  {
    GemmSide a{x_user, nullptr, wb + 0 * 4096, nullptr, (const float*)d_in[5],
               h_u, NU, 1, 0, tU};
    GemmSide b{x_item, nullptr, wb + 1 * 4096, nullptr, (const float*)d_in[7],
               h_i, NI, 1, 0, tI};
    k_dual_gemm<<<tU + tI, 256, 0, stream>>>(a, b);
  }

  // ---- CSR build (slotted aux; no pre-count) ----
  {
    BinASide a{u2i_src, u2i_dst, SH_I, nbI, gcurb_i, aux_i};
    BinASide b{i2u_src, i2u_dst, SH_U, nbU, gcurb_u, aux_u};
    k_dual_binA<<<2 * gA, 256, 0, stream>>>(a, b, E, gA);
  }
  k_bscan2<<<1, 512, 0, stream>>>(gcurb_i, nbI, gcurb_u, nbU, boff_i, boff_u);
  {
    BinBSide a{aux_i, gcurb_i, boff_i, SH_I, NI, off_i, csr_u2i, nbI};
    BinBSide b{aux_u, gcurb_u, boff_u, SH_U, NU, off_u, csr_i2u, nbU};
    k_dual_binB<<<nbI + nbU, 256, 0, stream>>>(a, b);
  }

  // ---- layer 1: both gathers in one dispatch, both convs in one ----
  {
    GathSide a{(const u32*)h_u, off_i, csr_u2i, (u32*)msg_i, NI, gGI};
    GathSide b{(const u32*)h_i, off_u, csr_i2u, (u32*)msg_u, NU, gGU};
    k_dual_gather<<<gGI + gGU, 256, 0, stream>>>(a, b);
  }
  {
    GemmSide a{msg_i, h_i, wb + 2 * 4096, wb + 3 * 4096, (const float*)d_in[9],
               x1_i, NI, 0, 1, tI};
    GemmSide b{msg_u, h_u, wb + 4 * 4096, wb + 5 * 4096, (const float*)d_in[12],
               x1_u, NU, 0, 1, tU};
    k_dual_gemm<<<tI + tU, 256, 0, stream>>>(a, b);
  }

  // ---- layer 2 (outputs overwrite h_i / h_u) ----
  {
    GathSide a{(const u32*)x1_u, off_i, csr_u2i, (u32*)msg_i, NI, gGI};
    GathSide b{(const u32*)x1_i, off_u, csr_i2u, (u32*)msg_u, NU, gGU};
    k_dual_gather<<<gGI + gGU, 256, 0, stream>>>(a, b);
  }
  {
    GemmSide a{msg_i, x1_i, wb + 6 * 4096, wb + 7 * 4096, (const float*)d_in[15],
               h_i, NI, 0, 1, tI};
    GemmSide b{msg_u, x1_u, wb + 8 * 4096, wb + 9 * 4096, (const float*)d_in[18],
               h_u, NU, 0, 1, tU};
    k_dual_gemm<<<tI + tU, 256, 0, stream>>>(a, b);
  }

  // ---- post linears (dual) -> fp32 d_out = [out_u | out_i] ----
  {
    float* out = (float*)d_out;
    PostSide a{h_u, wb + 10 * 4096, (const float*)d_in[21], out, NU, tU};
    PostSide b{h_i, wb + 11 * 4096, (const float*)d_in[23], out + (size_t)NU * 32, NI, tI};
    k_dual_postlin<<<tU + tI, 256, 0, stream>>>(a, b);
  }
}

// Round 4
// 432.834 us; speedup vs baseline: 1.4140x; 1.0185x over previous
//
#include <hip/hip_runtime.h>

// RGCN: hetero 2-layer GraphConv (mean aggr), MI355X.
// R10: gather VALU diet. R9's gather was VALU-issue-bound (VALUBusy 75%,
// HBM 34%): ~105 VALU/8-edge round, dominated by per-edge min-clamped csr
// addressing (~28 ops) + 64-bit row addr math (~24) + mask build (~16).
// New: (a) csr padded +16 zeros -> unclamped immediate-offset idx loads;
// (b) row addr = 32-bit byte offset (idx<<7 | c*4) off SGPR base;
// (c) full rounds unmasked, single masked tail round; (d) float2
// accumulators (v_pk_add candidates). ~46 VALU per full round.
// CSR build (R9 slotted), GEMMs unchanged.

#define FDIM 64
typedef unsigned short u16;
typedef unsigned int u32;
typedef __bf16 bf16x8 __attribute__((ext_vector_type(8)));
typedef float f32x4 __attribute__((ext_vector_type(4)));
typedef float f32x2 __attribute__((ext_vector_type(2)));

#define SLOT_S 3072

__device__ __forceinline__ u16 f2bf(float x) {  // RNE
  u32 b = __builtin_bit_cast(u32, x);
  b += 0x7FFFu + ((b >> 16) & 1u);
  return (u16)(b >> 16);
}
__device__ __forceinline__ float blo(u32 p) { return __builtin_bit_cast(float, p << 16); }
__device__ __forceinline__ float bhi(u32 p) { return __builtin_bit_cast(float, p & 0xffff0000u); }

// ---- weight conversion: 12 arrays fp32 -> bf16, optional +I (skip fold) ----
struct WTab {
  const float* src[12];
  u16* dst[12];
  int rows[12];
  int addI[12];
};
__global__ __launch_bounds__(256) void k_wconv(WTab p) {
  int b = blockIdx.x;
  const float* s = p.src[b];
  u16* d = p.dst[b];
  int n = p.rows[b] * 64;
  int addI = p.addI[b];
  for (int i = threadIdx.x; i < n; i += 256) {
    float v = s[i];
    if (addI && (i >> 6) == (i & 63)) v += 1.0f;
    d[i] = f2bf(v);
  }
}

// ---- init binA cursors to slot bases + zero csr pads ----
__global__ __launch_bounds__(256) void k_init_gcurb(int* __restrict__ gA, int nA,
                                                    int* __restrict__ gB, int nB,
                                                    int* __restrict__ padA,
                                                    int* __restrict__ padB) {
  int i = blockIdx.x * 256 + threadIdx.x;
  if (i < nA) gA[i] = i * SLOT_S;
  else if (i < nA + nB) gB[i - nA] = (i - nA) * SLOT_S;
  if (i < 16) { padA[i] = 0; padB[i] = 0; }
}

// ---- bucket scan (post-binA): counts = gcurb[b]-b*S, exclusive scan ----
__global__ __launch_bounds__(512) void k_bscan2(const int* __restrict__ gcA, int nbA,
                                                const int* __restrict__ gcB, int nbB,
                                                int* __restrict__ boffA,
                                                int* __restrict__ boffB) {
  __shared__ int sd[512];
  int t = threadIdx.x;
  for (int side = 0; side < 2; ++side) {
    const int* gc = side ? gcB : gcA;
    int nb = side ? nbB : nbA;
    int v = (t < nb) ? gc[t] - t * SLOT_S : 0;
    sd[t] = v; __syncthreads();
    int sum = v;
    for (int o = 1; o < 512; o <<= 1) {
      int x = (t >= o) ? sd[t - o] : 0;
      __syncthreads();
      sum += x; sd[t] = sum;
      __syncthreads();
    }
    int* bo = side ? boffB : boffA;
    if (t < nb) bo[t] = sum - v;
    if (t == nb - 1) bo[nb] = sum;
    __syncthreads();
  }
}

// ---- Pass A (dual): bin edges into per-bucket slot regions ----
#define PA_C 4096
struct BinASide {
  const int* src; const int* dst; int shift; int nb; int* gcurb; int2* aux;
};
__global__ __launch_bounds__(256) void k_dual_binA(BinASide A, BinASide B, int E, int gA) {
  int bid = blockIdx.x;
  const BinASide& P = (bid < gA) ? A : B;
  if (bid >= gA) bid -= gA;
  __shared__ int cnt[512];
  __shared__ int base[512];
  int t = threadIdx.x;
  int e0 = bid * PA_C;
  int n = min(PA_C, E - e0);
  int nb = P.nb, shift = P.shift;
  for (int b = t; b < nb; b += 256) cnt[b] = 0;
  __syncthreads();
  int ls[16], ld[16];
#pragma unroll
  for (int i = 0; i < 16; ++i) {
    int r = t + i * 256;
    if (r < n) {
      ls[i] = P.src[e0 + r];
      ld[i] = P.dst[e0 + r];
      atomicAdd(&cnt[ld[i] >> shift], 1);
    }
  }
  __syncthreads();
  for (int b = t; b < nb; b += 256) {
    int c = cnt[b];
    base[b] = c ? atomicAdd(&P.gcurb[b], c) : 0;
  }
  __syncthreads();
  for (int b = t; b < nb; b += 256) cnt[b] = 0;
  __syncthreads();
#pragma unroll
  for (int i = 0; i < 16; ++i) {
    int r = t + i * 256;
    if (r < n) {
      int b = ld[i] >> shift;
      int p = base[b] + atomicAdd(&cnt[b], 1);
      P.aux[p] = make_int2(ls[i], ld[i]);
    }
  }
}

// ---- Pass B (dual): per bucket -- LDS per-dst count + scan -> off[],
// then LDS-cursor scatter from slotted aux into compact csr ----
struct BinBSide {
  const int2* aux; const int* gcurb; const int* boff; int shift; int N;
  int* off; int* csr; int nblk;
};
__global__ __launch_bounds__(256) void k_dual_binB(BinBSide A, BinBSide B) {
  __shared__ int stage[4096];
  __shared__ int lcnt[512];
  __shared__ int sd[256];
  int b = blockIdx.x;
  const BinBSide& P = (b < A.nblk) ? A : B;
  if (b >= A.nblk) b -= A.nblk;
  int t = threadIdx.x;
  int d0 = b << P.shift;
  int d1 = min(d0 + (1 << P.shift), P.N);
  int nd = d1 - d0;
  size_t a0 = (size_t)b * SLOT_S;
  int r0 = P.boff[b];
  int RS = P.gcurb[b] - b * SLOT_S;
  for (int i = t; i < nd; i += 256) lcnt[i] = 0;
  __syncthreads();
  for (int i = t; i < RS; i += 256) {
    int2 p = P.aux[a0 + i];
    atomicAdd(&lcnt[p.y - d0], 1);
  }
  __syncthreads();
  // exclusive scan over nd (<=512) entries, 2 per thread
  int i0 = 2 * t, i1 = 2 * t + 1;
  int v0 = (i0 < nd) ? lcnt[i0] : 0;
  int v1 = (i1 < nd) ? lcnt[i1] : 0;
  int local = v0 + v1;
  sd[t] = local; __syncthreads();
  int sum = local;
  for (int o = 1; o < 256; o <<= 1) {
    int x = (t >= o) ? sd[t - o] : 0;
    __syncthreads();
    sum += x; sd[t] = sum;
    __syncthreads();
  }
  int run = sum - local;
  if (i0 < nd) { lcnt[i0] = run; P.off[d0 + i0] = r0 + run; }
  if (i1 < nd) { lcnt[i1] = run + v0; P.off[d0 + i1] = r0 + run + v0; }
  if (t == 0 && d1 == P.N) P.off[P.N] = r0 + RS;
  __syncthreads();
  if (RS <= 4096) {
    for (int i = t; i < RS; i += 256) {
      int2 p = P.aux[a0 + i];
      int pos = atomicAdd(&lcnt[p.y - d0], 1);
      stage[pos] = p.x;
    }
    __syncthreads();
    for (int i = t; i < RS; i += 256) P.csr[r0 + i] = stage[i];
  } else {
    for (int i = t; i < RS; i += 256) {
      int2 p = P.aux[a0 + i];
      int pos = atomicAdd(&lcnt[p.y - d0], 1);
      P.csr[r0 + pos] = p.x;
    }
  }
}

// ---- dual gather-mean: wave = 2 dsts; lane = (half h, u32 chunk c) ----
// R10: full rounds unmasked (csr padded +16 zeros makes overread safe:
// overread idx are valid node ids of the next rows, or 0 from the pad,
// and are excluded by the tail mask); 32-bit saddr row addressing;
// immediate-offset idx loads; pipelined idx prefetch; float2 accum.
struct GathSide {
  const u32* xs; const int* off; const int* csr; u32* msg; int N; int nblk;
};
__global__ __launch_bounds__(256) void k_dual_gather(GathSide A, GathSide B) {
  int bid = blockIdx.x;
  const GathSide& P = (bid < A.nblk) ? A : B;
  if (bid >= A.nblk) bid -= A.nblk;
  int lane = threadIdx.x & 63;
  int h = lane >> 5, c = lane & 31;
  int d = bid * 8 + (int)(threadIdx.x >> 6) * 2 + h;
  if (d >= P.N) return;
  int beg = P.off[d];
  int deg = P.off[d + 1] - beg;
  const char* xsb = (const char*)P.xs;
  const int* cp = P.csr + beg;
  u32 c4 = (u32)(c << 2);
  f32x2 s0 = {0.f, 0.f}, s1 = {0.f, 0.f};
  if (deg > 0) {
    int idx[8];
#pragma unroll
    for (int i = 0; i < 8; ++i) idx[i] = cp[i];  // overread <=7: pad-safe
    int j = 0;
    for (; j + 8 <= deg; j += 8) {  // full rounds, no mask
      u32 p[8];
#pragma unroll
      for (int i = 0; i < 8; ++i)
        p[i] = *(const u32*)(xsb + (size_t)((((u32)idx[i]) << 7) | c4));
#pragma unroll
      for (int i = 0; i < 8; ++i) idx[i] = cp[j + 8 + i];  // overread <=15: pad-safe
#pragma unroll
      for (int i = 0; i < 8; ++i) {
        f32x2 v = {blo(p[i]), bhi(p[i])};
        if (i & 1) s1 += v; else s0 += v;
      }
    }
    if (j < deg) {  // single masked tail round (idx already loaded)
      u32 p[8];
#pragma unroll
      for (int i = 0; i < 8; ++i)
        p[i] = *(const u32*)(xsb + (size_t)((((u32)idx[i]) << 7) | c4));
#pragma unroll
      for (int i = 0; i < 8; ++i) {
        float m = (j + i < deg) ? 1.0f : 0.0f;
        f32x2 v = {blo(p[i]) * m, bhi(p[i]) * m};
        if (i & 1) s1 += v; else s0 += v;
      }
    }
  }
  f32x2 s = s0 + s1;
  float sc = 1.0f / fmaxf((float)deg, 1.0f);
  P.msg[(size_t)d * 32 + c] = (u32)f2bf(s.x * sc) | ((u32)f2bf(s.y * sc) << 16);
}

// ---- dual MFMA GEMM: Y[N,64](bf16) = act( A1 @ W1^T [+ A2 @ W2^T] + bias )
// 128-row tile, wave = 32 rows x 64 cols, direct fragment loads, no LDS.
// Layouts (m89/m91/m120): A-frag A[m=lane&15][k=q*8+j]; B-frag = rows of W;
// C/D col=lane&15, row=q*4+reg.
struct GemmSide {
  const void* A1; const u16* A2; const u16* W1; const u16* W2;
  const float* bias; u16* Y; int N; int a1fp32; int dorelu; int nblk;
};
__device__ __forceinline__ void gemm64_body(const GemmSide& P, int bid) {
  const int t = threadIdx.x;
  const int w = t >> 6, lane = t & 63;
  const int c = lane & 15, q = lane >> 4;
  const int row0 = bid * 128 + w * 32;

  bf16x8 zf;
#pragma unroll
  for (int i = 0; i < 8; ++i) zf[i] = (__bf16)0.0f;

  f32x4 acc[2][4];
#pragma unroll
  for (int ms = 0; ms < 2; ++ms)
#pragma unroll
    for (int n = 0; n < 4; ++n) acc[ms][n] = f32x4{0.f, 0.f, 0.f, 0.f};

  const int nh = (P.A2 != nullptr) ? 2 : 1;
  for (int hh = 0; hh < nh; ++hh) {
    const u16* W = hh ? P.W2 : P.W1;
    bf16x8 bfr[4][2];
#pragma unroll
    for (int n = 0; n < 4; ++n)
#pragma unroll
      for (int kc = 0; kc < 2; ++kc)
        bfr[n][kc] = *(const bf16x8*)(W + (n * 16 + c) * 64 + kc * 32 + q * 8);
    bf16x8 afr[2][2];
#pragma unroll
    for (int ms = 0; ms < 2; ++ms) {
      int row = row0 + ms * 16 + c;
      bool ok = row < P.N;
#pragma unroll
      for (int kc = 0; kc < 2; ++kc) {
        if (hh == 0 && P.a1fp32) {
          bf16x8 v = zf;
          if (ok) {
            const float* Af = (const float*)P.A1 + (size_t)row * 64 + kc * 32 + q * 8;
            float4 u0 = *(const float4*)Af;
            float4 u1 = *(const float4*)(Af + 4);
            v[0] = (__bf16)u0.x; v[1] = (__bf16)u0.y; v[2] = (__bf16)u0.z; v[3] = (__bf16)u0.w;
            v[4] = (__bf16)u1.x; v[5] = (__bf16)u1.y; v[6] = (__bf16)u1.z; v[7] = (__bf16)u1.w;
          }
          afr[ms][kc] = v;
        } else {
          const u16* Ab = (hh == 0) ? (const u16*)P.A1 : P.A2;
          afr[ms][kc] = ok ? *(const bf16x8*)(Ab + (size_t)row * 64 + kc * 32 + q * 8) : zf;
        }
      }
    }
#pragma unroll
    for (int n = 0; n < 4; ++n)
#pragma unroll
      for (int ms = 0; ms < 2; ++ms)
#pragma unroll
        for (int kc = 0; kc < 2; ++kc)
          acc[ms][n] = __builtin_amdgcn_mfma_f32_16x16x32_bf16(afr[ms][kc], bfr[n][kc],
                                                               acc[ms][n], 0, 0, 0);
  }
#pragma unroll
  for (int n = 0; n < 4; ++n) {
    float bv = P.bias[n * 16 + c];
#pragma unroll
    for (int ms = 0; ms < 2; ++ms) {
#pragma unroll
      for (int r = 0; r < 4; ++r) {
        int row = row0 + ms * 16 + q * 4 + r;
        if (row < P.N) {
          float v = acc[ms][n][r] + bv;
          if (P.dorelu) v = fmaxf(v, 0.f);
          P.Y[(size_t)row * 64 + n * 16 + c] = f2bf(v);
        }
      }
    }
  }
}
__global__ __launch_bounds__(256) void k_dual_gemm(GemmSide A, GemmSide B) {
  if ((int)blockIdx.x < A.nblk) gemm64_body(A, blockIdx.x);
  else gemm64_body(B, blockIdx.x - A.nblk);
}

// ---- dual MFMA post linear: Y[N,32](fp32) = A(bf16) @ W[32,64]^T + bias ----
struct PostSide {
  const u16* A; const u16* W; const float* bias; float* Y; int N; int nblk;
};
__device__ __forceinline__ void postlin_body(const PostSide& P, int bid) {
  const int t = threadIdx.x;
  const int w = t >> 6, lane = t & 63;
  const int c = lane & 15, q = lane >> 4;
  const int row0 = bid * 128 + w * 32;

  bf16x8 zf;
#pragma unroll
  for (int i = 0; i < 8; ++i) zf[i] = (__bf16)0.0f;

  f32x4 acc[2][2];
#pragma unroll
  for (int ms = 0; ms < 2; ++ms)
#pragma unroll
    for (int n = 0; n < 2; ++n) acc[ms][n] = f32x4{0.f, 0.f, 0.f, 0.f};

  bf16x8 bfr[2][2];
#pragma unroll
  for (int n = 0; n < 2; ++n)
#pragma unroll
    for (int kc = 0; kc < 2; ++kc)
      bfr[n][kc] = *(const bf16x8*)(P.W + (n * 16 + c) * 64 + kc * 32 + q * 8);
  bf16x8 afr[2][2];
#pragma unroll
  for (int ms = 0; ms < 2; ++ms) {
    int row = row0 + ms * 16 + c;
    bool ok = row < P.N;
#pragma unroll
    for (int kc = 0; kc < 2; ++kc)
      afr[ms][kc] = ok ? *(const bf16x8*)(P.A + (size_t)row * 64 + kc * 32 + q * 8) : zf;
  }
#pragma unroll
  for (int n = 0; n < 2; ++n)
#pragma unroll
    for (int ms = 0; ms < 2; ++ms)
#pragma unroll
      for (int kc = 0; kc < 2; ++kc)
        acc[ms][n] = __builtin_amdgcn_mfma_f32_16x16x32_bf16(afr[ms][kc], bfr[n][kc],
                                                             acc[ms][n], 0, 0, 0);
#pragma unroll
  for (int n = 0; n < 2; ++n) {
    float bv = P.bias[n * 16 + c];
#pragma unroll
    for (int ms = 0; ms < 2; ++ms) {
#pragma unroll
      for (int r = 0; r < 4; ++r) {
        int row = row0 + ms * 16 + q * 4 + r;
        if (row < P.N) P.Y[(size_t)row * 32 + n * 16 + c] = acc[ms][n][r] + bv;
      }
    }
  }
}
__global__ __launch_bounds__(256) void k_dual_postlin(PostSide A, PostSide B) {
  if ((int)blockIdx.x < A.nblk) postlin_body(A, blockIdx.x);
  else postlin_body(B, blockIdx.x - A.nblk);
}

extern "C" void kernel_launch(void* const* d_in, const int* in_sizes, int n_in,
                              void* d_out, int out_size, void* d_ws, size_t ws_size,
                              hipStream_t stream) {
  const float* x_user = (const float*)d_in[0];
  const float* x_item = (const float*)d_in[1];
  const int* ei_u2i = (const int*)d_in[2];
  const int* ei_i2u = (const int*)d_in[3];

  const int NU = in_sizes[0] / FDIM;
  const int NI = in_sizes[1] / FDIM;
  const int E = in_sizes[2] / 2;

  const int SH_I = 8, SH_U = 9;
  const int nbI = (NI + (1 << SH_I) - 1) >> SH_I;
  const int nbU = (NU + (1 << SH_U) - 1) >> SH_U;

  // ---- workspace ----
  u16* wsu = (u16*)d_ws;
  u16* h_u = wsu;   wsu += (size_t)NU * FDIM;
  u16* h_i = wsu;   wsu += (size_t)NI * FDIM;
  u16* x1_u = wsu;  wsu += (size_t)NU * FDIM;
  u16* x1_i = wsu;  wsu += (size_t)NI * FDIM;
  u16* msg_i = wsu; wsu += (size_t)NI * FDIM;
  u16* msg_u = wsu; wsu += (size_t)NU * FDIM;
  u16* wb = wsu;    wsu += 12 * 4096;
  int2* aux_i = (int2*)wsu;
  int2* aux_u = aux_i + (size_t)nbI * SLOT_S;
  int* wsi = (int*)(aux_u + (size_t)nbU * SLOT_S);
  int* off_i = wsi;    wsi += NI + 1;
  int* off_u = wsi;    wsi += NU + 1;
  int* boff_i = wsi;   wsi += nbI + 1;
  int* boff_u = wsi;   wsi += nbU + 1;
  int* gcurb_i = wsi;  wsi += 512;
  int* gcurb_u = wsi;  wsi += 512;
  int* csr_u2i = wsi;  wsi += E + 16;  // +16 pad for unclamped overread
  int* csr_i2u = wsi;  wsi += E + 16;

  const int* u2i_src = ei_u2i;
  const int* u2i_dst = ei_u2i + E;
  const int* i2u_src = ei_i2u;
  const int* i2u_dst = ei_i2u + E;

  const int gA = (E + PA_C - 1) / PA_C;
  const int tU = (NU + 127) / 128;
  const int tI = (NI + 127) / 128;
  const int gGI = (NI + 7) / 8;
  const int gGU = (NU + 7) / 8;

  // ---- weight conversion (skip folded: wroot + I) ----
  WTab tab;
  const int widx[12] = {4, 6, 8, 10, 11, 13, 14, 16, 17, 19, 20, 22};
  const int addI[12] = {0, 0, 0, 1, 0, 1, 0, 1, 0, 1, 0, 0};
  const int rows_[12] = {64, 64, 64, 64, 64, 64, 64, 64, 64, 64, 32, 32};
  for (int i = 0; i < 12; ++i) {
    tab.src[i] = (const float*)d_in[widx[i]];
    tab.dst[i] = wb + i * 4096;
    tab.rows[i] = rows_[i];
    tab.addI[i] = addI[i];
  }
  k_wconv<<<12, 256, 0, stream>>>(tab);
  k_init_gcurb<<<(nbI + nbU + 255) / 256, 256, 0, stream>>>(gcurb_i, nbI, gcurb_u, nbU,
                                                            csr_u2i + E, csr_i2u + E);

  // ---- pre linears (dual): fp32 x -> bf16 h ----
  {
    GemmSide a{x_user, nullptr, wb + 0 * 4096, nullptr, (const float*)d_in[5],
               h_u, NU, 1, 0, tU};
    GemmSide b{x_item, nullptr, wb + 1 * 4096, nullptr, (const float*)d_in[7],
               h_i, NI, 1, 0, tI};
    k_dual_gemm<<<tU + tI, 256, 0, stream>>>(a, b);
  }

  // ---- CSR build (slotted aux; no pre-count) ----
  {
    BinASide a{u2i_src, u2i_dst, SH_I, nbI, gcurb_i, aux_i};
    BinASide b{i2u_src, i2u_dst, SH_U, nbU, gcurb_u, aux_u};
    k_dual_binA<<<2 * gA, 256, 0, stream>>>(a, b, E, gA);
  }
  k_bscan2<<<1, 512, 0, stream>>>(gcurb_i, nbI, gcurb_u, nbU, boff_i, boff_u);
  {
    BinBSide a{aux_i, gcurb_i, boff_i, SH_I, NI, off_i, csr_u2i, nbI};
    BinBSide b{aux_u, gcurb_u, boff_u, SH_U, NU, off_u, csr_i2u, nbU};
    k_dual_binB<<<nbI + nbU, 256, 0, stream>>>(a, b);
  }

  // ---- layer 1: both gathers in one dispatch, both convs in one ----
  {
    GathSide a{(const u32*)h_u, off_i, csr_u2i, (u32*)msg_i, NI, gGI};
    GathSide b{(const u32*)h_i, off_u, csr_i2u, (u32*)msg_u, NU, gGU};
    k_dual_gather<<<gGI + gGU, 256, 0, stream>>>(a, b);
  }
  {
    GemmSide a{msg_i, h_i, wb + 2 * 4096, wb + 3 * 4096, (const float*)d_in[9],
               x1_i, NI, 0, 1, tI};
    GemmSide b{msg_u, h_u, wb + 4 * 4096, wb + 5 * 4096, (const float*)d_in[12],
               x1_u, NU, 0, 1, tU};
    k_dual_gemm<<<tI + tU, 256, 0, stream>>>(a, b);
  }

  // ---- layer 2 (outputs overwrite h_i / h_u) ----
  {
    GathSide a{(const u32*)x1_u, off_i, csr_u2i, (u32*)msg_i, NI, gGI};
    GathSide b{(const u32*)x1_i, off_u, csr_i2u, (u32*)msg_u, NU, gGU};
    k_dual_gather<<<gGI + gGU, 256, 0, stream>>>(a, b);
  }
  {
    GemmSide a{msg_i, x1_i, wb + 6 * 4096, wb + 7 * 4096, (const float*)d_in[15],
               h_i, NI, 0, 1, tI};
    GemmSide b{msg_u, x1_u, wb + 8 * 4096, wb + 9 * 4096, (const float*)d_in[18],
               h_u, NU, 0, 1, tU};
    k_dual_gemm<<<tI + tU, 256, 0, stream>>>(a, b);
  }

  // ---- post linears (dual) -> fp32 d_out = [out_u | out_i] ----
  {
    float* out = (float*)d_out;
    PostSide a{h_u, wb + 10 * 4096, (const float*)d_in[21], out, NU, tU};
    PostSide b{h_i, wb + 11 * 4096, (const float*)d_in[23], out + (size_t)NU * 32, NI, tI};
    k_dual_postlin<<<tU + tI, 256, 0, stream>>>(a, b);
  }
}

// Round 7
// 403.349 us; speedup vs baseline: 1.5173x; 1.0731x over previous
//
#include <hip/hip_runtime.h>

// RGCN: hetero 2-layer GraphConv (mean aggr), MI355X.
// R11 (2nd resubmit; two consecutive GPUAcquisitionTimeouts -- broker at
// capacity, kernel never ran; code unchanged, no data to act on).
// Pipelined multi-tile GEMM. R10's gemm dispatches were pure exposed
// latency (MfmaUtil 1.6%, VALU 10%, HBM 18%, ~15us wave lifetime for
// ~1us of work): 2345 one-tile blocks each paid a full memory latency.
// New: TPB_G=4 tiles per block, W+bias loaded once per wave, A-fragments
// double-buffered in registers (issue t+1 -> mfma+store t -> swap).
// Pre (fp32-A) and conv (dual bf16-A) are separate kernels so register
// budgets stay per-case. Gather (R10), CSR build (R9), postlin unchanged.

#define FDIM 64
typedef unsigned short u16;
typedef unsigned int u32;
typedef __bf16 bf16x8 __attribute__((ext_vector_type(8)));
typedef float f32x4 __attribute__((ext_vector_type(4)));
typedef float f32x2 __attribute__((ext_vector_type(2)));

#define SLOT_S 3072
#define TPB_G 4

__device__ __forceinline__ u16 f2bf(float x) {  // RNE
  u32 b = __builtin_bit_cast(u32, x);
  b += 0x7FFFu + ((b >> 16) & 1u);
  return (u16)(b >> 16);
}
__device__ __forceinline__ float blo(u32 p) { return __builtin_bit_cast(float, p << 16); }
__device__ __forceinline__ float bhi(u32 p) { return __builtin_bit_cast(float, p & 0xffff0000u); }

// ---- weight conversion: 12 arrays fp32 -> bf16, optional +I (skip fold) ----
struct WTab {
  const float* src[12];
  u16* dst[12];
  int rows[12];
  int addI[12];
};
__global__ __launch_bounds__(256) void k_wconv(WTab p) {
  int b = blockIdx.x;
  const float* s = p.src[b];
  u16* d = p.dst[b];
  int n = p.rows[b] * 64;
  int addI = p.addI[b];
  for (int i = threadIdx.x; i < n; i += 256) {
    float v = s[i];
    if (addI && (i >> 6) == (i & 63)) v += 1.0f;
    d[i] = f2bf(v);
  }
}

// ---- init binA cursors to slot bases + zero csr pads ----
__global__ __launch_bounds__(256) void k_init_gcurb(int* __restrict__ gA, int nA,
                                                    int* __restrict__ gB, int nB,
                                                    int* __restrict__ padA,
                                                    int* __restrict__ padB) {
  int i = blockIdx.x * 256 + threadIdx.x;
  if (i < nA) gA[i] = i * SLOT_S;
  else if (i < nA + nB) gB[i - nA] = (i - nA) * SLOT_S;
  if (i < 16) { padA[i] = 0; padB[i] = 0; }
}

// ---- bucket scan (post-binA): counts = gcurb[b]-b*S, exclusive scan ----
__global__ __launch_bounds__(512) void k_bscan2(const int* __restrict__ gcA, int nbA,
                                                const int* __restrict__ gcB, int nbB,
                                                int* __restrict__ boffA,
                                                int* __restrict__ boffB) {
  __shared__ int sd[512];
  int t = threadIdx.x;
  for (int side = 0; side < 2; ++side) {
    const int* gc = side ? gcB : gcA;
    int nb = side ? nbB : nbA;
    int v = (t < nb) ? gc[t] - t * SLOT_S : 0;
    sd[t] = v; __syncthreads();
    int sum = v;
    for (int o = 1; o < 512; o <<= 1) {
      int x = (t >= o) ? sd[t - o] : 0;
      __syncthreads();
      sum += x; sd[t] = sum;
      __syncthreads();
    }
    int* bo = side ? boffB : boffA;
    if (t < nb) bo[t] = sum - v;
    if (t == nb - 1) bo[nb] = sum;
    __syncthreads();
  }
}

// ---- Pass A (dual): bin edges into per-bucket slot regions ----
#define PA_C 4096
struct BinASide {
  const int* src; const int* dst; int shift; int nb; int* gcurb; int2* aux;
};
__global__ __launch_bounds__(256) void k_dual_binA(BinASide A, BinASide B, int E, int gA) {
  int bid = blockIdx.x;
  const BinASide& P = (bid < gA) ? A : B;
  if (bid >= gA) bid -= gA;
  __shared__ int cnt[512];
  __shared__ int base[512];
  int t = threadIdx.x;
  int e0 = bid * PA_C;
  int n = min(PA_C, E - e0);
  int nb = P.nb, shift = P.shift;
  for (int b = t; b < nb; b += 256) cnt[b] = 0;
  __syncthreads();
  int ls[16], ld[16];
#pragma unroll
  for (int i = 0; i < 16; ++i) {
    int r = t + i * 256;
    if (r < n) {
      ls[i] = P.src[e0 + r];
      ld[i] = P.dst[e0 + r];
      atomicAdd(&cnt[ld[i] >> shift], 1);
    }
  }
  __syncthreads();
  for (int b = t; b < nb; b += 256) {
    int c = cnt[b];
    base[b] = c ? atomicAdd(&P.gcurb[b], c) : 0;
  }
  __syncthreads();
  for (int b = t; b < nb; b += 256) cnt[b] = 0;
  __syncthreads();
#pragma unroll
  for (int i = 0; i < 16; ++i) {
    int r = t + i * 256;
    if (r < n) {
      int b = ld[i] >> shift;
      int p = base[b] + atomicAdd(&cnt[b], 1);
      P.aux[p] = make_int2(ls[i], ld[i]);
    }
  }
}

// ---- Pass B (dual): per bucket -- LDS per-dst count + scan -> off[],
// then LDS-cursor scatter from slotted aux into compact csr ----
struct BinBSide {
  const int2* aux; const int* gcurb; const int* boff; int shift; int N;
  int* off; int* csr; int nblk;
};
__global__ __launch_bounds__(256) void k_dual_binB(BinBSide A, BinBSide B) {
  __shared__ int stage[4096];
  __shared__ int lcnt[512];
  __shared__ int sd[256];
  int b = blockIdx.x;
  const BinBSide& P = (b < A.nblk) ? A : B;
  if (b >= A.nblk) b -= A.nblk;
  int t = threadIdx.x;
  int d0 = b << P.shift;
  int d1 = min(d0 + (1 << P.shift), P.N);
  int nd = d1 - d0;
  size_t a0 = (size_t)b * SLOT_S;
  int r0 = P.boff[b];
  int RS = P.gcurb[b] - b * SLOT_S;
  for (int i = t; i < nd; i += 256) lcnt[i] = 0;
  __syncthreads();
  for (int i = t; i < RS; i += 256) {
    int2 p = P.aux[a0 + i];
    atomicAdd(&lcnt[p.y - d0], 1);
  }
  __syncthreads();
  // exclusive scan over nd (<=512) entries, 2 per thread
  int i0 = 2 * t, i1 = 2 * t + 1;
  int v0 = (i0 < nd) ? lcnt[i0] : 0;
  int v1 = (i1 < nd) ? lcnt[i1] : 0;
  int local = v0 + v1;
  sd[t] = local; __syncthreads();
  int sum = local;
  for (int o = 1; o < 256; o <<= 1) {
    int x = (t >= o) ? sd[t - o] : 0;
    __syncthreads();
    sum += x; sd[t] = sum;
    __syncthreads();
  }
  int run = sum - local;
  if (i0 < nd) { lcnt[i0] = run; P.off[d0 + i0] = r0 + run; }
  if (i1 < nd) { lcnt[i1] = run + v0; P.off[d0 + i1] = r0 + run + v0; }
  if (t == 0 && d1 == P.N) P.off[P.N] = r0 + RS;
  __syncthreads();
  if (RS <= 4096) {
    for (int i = t; i < RS; i += 256) {
      int2 p = P.aux[a0 + i];
      int pos = atomicAdd(&lcnt[p.y - d0], 1);
      stage[pos] = p.x;
    }
    __syncthreads();
    for (int i = t; i < RS; i += 256) P.csr[r0 + i] = stage[i];
  } else {
    for (int i = t; i < RS; i += 256) {
      int2 p = P.aux[a0 + i];
      int pos = atomicAdd(&lcnt[p.y - d0], 1);
      P.csr[r0 + pos] = p.x;
    }
  }
}

// ---- dual gather-mean: wave = 2 dsts; lane = (half h, u32 chunk c) ----
// R10: full rounds unmasked (csr padded +16 zeros), 32-bit saddr row
// addressing, immediate-offset idx loads, pipelined prefetch, f32x2 acc.
struct GathSide {
  const u32* xs; const int* off; const int* csr; u32* msg; int N; int nblk;
};
__global__ __launch_bounds__(256) void k_dual_gather(GathSide A, GathSide B) {
  int bid = blockIdx.x;
  const GathSide& P = (bid < A.nblk) ? A : B;
  if (bid >= A.nblk) bid -= A.nblk;
  int lane = threadIdx.x & 63;
  int h = lane >> 5, c = lane & 31;
  int d = bid * 8 + (int)(threadIdx.x >> 6) * 2 + h;
  if (d >= P.N) return;
  int beg = P.off[d];
  int deg = P.off[d + 1] - beg;
  const char* xsb = (const char*)P.xs;
  const int* cp = P.csr + beg;
  u32 c4 = (u32)(c << 2);
  f32x2 s0 = {0.f, 0.f}, s1 = {0.f, 0.f};
  if (deg > 0) {
    int idx[8];
#pragma unroll
    for (int i = 0; i < 8; ++i) idx[i] = cp[i];  // overread <=7: pad-safe
    int j = 0;
    for (; j + 8 <= deg; j += 8) {  // full rounds, no mask
      u32 p[8];
#pragma unroll
      for (int i = 0; i < 8; ++i)
        p[i] = *(const u32*)(xsb + (size_t)((((u32)idx[i]) << 7) | c4));
#pragma unroll
      for (int i = 0; i < 8; ++i) idx[i] = cp[j + 8 + i];  // overread <=15: pad-safe
#pragma unroll
      for (int i = 0; i < 8; ++i) {
        f32x2 v = {blo(p[i]), bhi(p[i])};
        if (i & 1) s1 += v; else s0 += v;
      }
    }
    if (j < deg) {  // single masked tail round (idx already loaded)
      u32 p[8];
#pragma unroll
      for (int i = 0; i < 8; ++i)
        p[i] = *(const u32*)(xsb + (size_t)((((u32)idx[i]) << 7) | c4));
#pragma unroll
      for (int i = 0; i < 8; ++i) {
        float m = (j + i < deg) ? 1.0f : 0.0f;
        f32x2 v = {blo(p[i]) * m, bhi(p[i]) * m};
        if (i & 1) s1 += v; else s0 += v;
      }
    }
  }
  f32x2 s = s0 + s1;
  float sc = 1.0f / fmaxf((float)deg, 1.0f);
  P.msg[(size_t)d * 32 + c] = (u32)f2bf(s.x * sc) | ((u32)f2bf(s.y * sc) << 16);
}

// ---- pipelined MFMA GEMMs: Y[N,64](bf16) = act( A1@W1^T [+ A2@W2^T] + b )
// Block = TPB_G consecutive 128-row tiles; wave = 32 rows x 64 cols.
// W frags + bias in registers once per wave; A frags double-buffered.
// Layouts (m89/m91/m120): A-frag A[m=lane&15][k=q*8+j]; B-frag = rows of W;
// C/D col=lane&15, row=q*4+reg.
struct GemmSide {
  const void* A1; const u16* A2; const u16* W1; const u16* W2;
  const float* bias; u16* Y; int N; int dorelu; int ntile; int nblk;
};

__device__ __forceinline__ void conv_body(const GemmSide& P, int bid) {
  const int t = threadIdx.x;
  const int w = t >> 6, lane = t & 63;
  const int c = lane & 15, q = lane >> 4;
  int t0 = bid * TPB_G;
  int t1 = min(t0 + TPB_G, P.ntile);

  bf16x8 zf;
#pragma unroll
  for (int i = 0; i < 8; ++i) zf[i] = (__bf16)0.0f;

  bf16x8 wf[2][4][2];
#pragma unroll
  for (int hh = 0; hh < 2; ++hh)
#pragma unroll
    for (int n = 0; n < 4; ++n)
#pragma unroll
      for (int kc = 0; kc < 2; ++kc)
        wf[hh][n][kc] = *(const bf16x8*)((hh ? P.W2 : P.W1) + (n * 16 + c) * 64 + kc * 32 + q * 8);
  float bv[4];
#pragma unroll
  for (int n = 0; n < 4; ++n) bv[n] = P.bias[n * 16 + c];

  const u16* A1 = (const u16*)P.A1;
  const u16* A2 = P.A2;

  bf16x8 aX[2][2][2], aY[2][2][2];  // [hh][ms][kc]

  auto issue = [&](int tt, bf16x8 (&buf)[2][2][2]) {
#pragma unroll
    for (int ms = 0; ms < 2; ++ms) {
      int row = tt * 128 + w * 32 + ms * 16 + c;
      bool ok = row < P.N;
#pragma unroll
      for (int kc = 0; kc < 2; ++kc) {
        buf[0][ms][kc] = ok ? *(const bf16x8*)(A1 + (size_t)row * 64 + kc * 32 + q * 8) : zf;
        buf[1][ms][kc] = ok ? *(const bf16x8*)(A2 + (size_t)row * 64 + kc * 32 + q * 8) : zf;
      }
    }
  };
  auto work = [&](int tt, bf16x8 (&buf)[2][2][2]) {
    f32x4 acc[2][4];
#pragma unroll
    for (int ms = 0; ms < 2; ++ms)
#pragma unroll
      for (int n = 0; n < 4; ++n) acc[ms][n] = f32x4{0.f, 0.f, 0.f, 0.f};
#pragma unroll
    for (int hh = 0; hh < 2; ++hh)
#pragma unroll
      for (int n = 0; n < 4; ++n)
#pragma unroll
        for (int ms = 0; ms < 2; ++ms)
#pragma unroll
          for (int kc = 0; kc < 2; ++kc)
            acc[ms][n] = __builtin_amdgcn_mfma_f32_16x16x32_bf16(buf[hh][ms][kc], wf[hh][n][kc],
                                                                 acc[ms][n], 0, 0, 0);
    int row0 = tt * 128 + w * 32;
#pragma unroll
    for (int n = 0; n < 4; ++n) {
#pragma unroll
      for (int ms = 0; ms < 2; ++ms) {
#pragma unroll
        for (int r = 0; r < 4; ++r) {
          int row = row0 + ms * 16 + q * 4 + r;
          if (row < P.N) {
            float v = acc[ms][n][r] + bv[n];
            if (P.dorelu) v = fmaxf(v, 0.f);
            P.Y[(size_t)row * 64 + n * 16 + c] = f2bf(v);
          }
        }
      }
    }
  };

  int tt = t0;
  issue(tt, aX);
  for (; tt + 2 <= t1; tt += 2) {
    issue(tt + 1, aY);
    work(tt, aX);
    if (tt + 2 < t1) issue(tt + 2, aX);
    work(tt + 1, aY);
  }
  if (tt < t1) work(tt, aX);
}
__global__ __launch_bounds__(256) void k_dual_conv_gemm(GemmSide A, GemmSide B) {
  if ((int)blockIdx.x < A.nblk) conv_body(A, blockIdx.x);
  else conv_body(B, blockIdx.x - A.nblk);
}

__device__ __forceinline__ void pre_body(const GemmSide& P, int bid) {
  const int t = threadIdx.x;
  const int w = t >> 6, lane = t & 63;
  const int c = lane & 15, q = lane >> 4;
  int t0 = bid * TPB_G;
  int t1 = min(t0 + TPB_G, P.ntile);

  bf16x8 wf[4][2];
#pragma unroll
  for (int n = 0; n < 4; ++n)
#pragma unroll
    for (int kc = 0; kc < 2; ++kc)
      wf[n][kc] = *(const bf16x8*)(P.W1 + (n * 16 + c) * 64 + kc * 32 + q * 8);
  float bv[4];
#pragma unroll
  for (int n = 0; n < 4; ++n) bv[n] = P.bias[n * 16 + c];

  const float* A1 = (const float*)P.A1;

  f32x4 rX[2][2][2], rY[2][2][2];  // [ms][kc][half]

  auto issue = [&](int tt, f32x4 (&buf)[2][2][2]) {
#pragma unroll
    for (int ms = 0; ms < 2; ++ms) {
      int row = tt * 128 + w * 32 + ms * 16 + c;
      bool ok = row < P.N;
#pragma unroll
      for (int kc = 0; kc < 2; ++kc) {
        const float* Af = A1 + (size_t)row * 64 + kc * 32 + q * 8;
        buf[ms][kc][0] = ok ? *(const f32x4*)Af : f32x4{0.f, 0.f, 0.f, 0.f};
        buf[ms][kc][1] = ok ? *(const f32x4*)(Af + 4) : f32x4{0.f, 0.f, 0.f, 0.f};
      }
    }
  };
  auto work = [&](int tt, f32x4 (&buf)[2][2][2]) {
    f32x4 acc[2][4];
#pragma unroll
    for (int ms = 0; ms < 2; ++ms)
#pragma unroll
      for (int n = 0; n < 4; ++n) acc[ms][n] = f32x4{0.f, 0.f, 0.f, 0.f};
    bf16x8 afr[2][2];
#pragma unroll
    for (int ms = 0; ms < 2; ++ms)
#pragma unroll
      for (int kc = 0; kc < 2; ++kc) {
        bf16x8 v;
#pragma unroll
        for (int i = 0; i < 4; ++i) {
          v[i] = (__bf16)buf[ms][kc][0][i];
          v[4 + i] = (__bf16)buf[ms][kc][1][i];
        }
        afr[ms][kc] = v;
      }
#pragma unroll
    for (int n = 0; n < 4; ++n)
#pragma unroll
      for (int ms = 0; ms < 2; ++ms)
#pragma unroll
        for (int kc = 0; kc < 2; ++kc)
          acc[ms][n] = __builtin_amdgcn_mfma_f32_16x16x32_bf16(afr[ms][kc], wf[n][kc],
                                                               acc[ms][n], 0, 0, 0);
    int row0 = tt * 128 + w * 32;
#pragma unroll
    for (int n = 0; n < 4; ++n) {
#pragma unroll
      for (int ms = 0; ms < 2; ++ms) {
#pragma unroll
        for (int r = 0; r < 4; ++r) {
          int row = row0 + ms * 16 + q * 4 + r;
          if (row < P.N) P.Y[(size_t)row * 64 + n * 16 + c] = f2bf(acc[ms][n][r] + bv[n]);
        }
      }
    }
  };

  int tt = t0;
  issue(tt, rX);
  for (; tt + 2 <= t1; tt += 2) {
    issue(tt + 1, rY);
    work(tt, rX);
    if (tt + 2 < t1) issue(tt + 2, rX);
    work(tt + 1, rY);
  }
  if (tt < t1) work(tt, rX);
}
__global__ __launch_bounds__(256) void k_dual_pre_gemm(GemmSide A, GemmSide B) {
  if ((int)blockIdx.x < A.nblk) pre_body(A, blockIdx.x);
  else pre_body(B, blockIdx.x - A.nblk);
}

// ---- dual MFMA post linear: Y[N,32](fp32) = A(bf16) @ W[32,64]^T + bias ----
struct PostSide {
  const u16* A; const u16* W; const float* bias; float* Y; int N; int nblk;
};
__device__ __forceinline__ void postlin_body(const PostSide& P, int bid) {
  const int t = threadIdx.x;
  const int w = t >> 6, lane = t & 63;
  const int c = lane & 15, q = lane >> 4;
  const int row0 = bid * 128 + w * 32;

  bf16x8 zf;
#pragma unroll
  for (int i = 0; i < 8; ++i) zf[i] = (__bf16)0.0f;

  f32x4 acc[2][2];
#pragma unroll
  for (int ms = 0; ms < 2; ++ms)
#pragma unroll
    for (int n = 0; n < 2; ++n) acc[ms][n] = f32x4{0.f, 0.f, 0.f, 0.f};

  bf16x8 bfr[2][2];
#pragma unroll
  for (int n = 0; n < 2; ++n)
#pragma unroll
    for (int kc = 0; kc < 2; ++kc)
      bfr[n][kc] = *(const bf16x8*)(P.W + (n * 16 + c) * 64 + kc * 32 + q * 8);
  bf16x8 afr[2][2];
#pragma unroll
  for (int ms = 0; ms < 2; ++ms) {
    int row = row0 + ms * 16 + c;
    bool ok = row < P.N;
#pragma unroll
    for (int kc = 0; kc < 2; ++kc)
      afr[ms][kc] = ok ? *(const bf16x8*)(P.A + (size_t)row * 64 + kc * 32 + q * 8) : zf;
  }
#pragma unroll
  for (int n = 0; n < 2; ++n)
#pragma unroll
    for (int ms = 0; ms < 2; ++ms)
#pragma unroll
      for (int kc = 0; kc < 2; ++kc)
        acc[ms][n] = __builtin_amdgcn_mfma_f32_16x16x32_bf16(afr[ms][kc], bfr[n][kc],
                                                             acc[ms][n], 0, 0, 0);
#pragma unroll
  for (int n = 0; n < 2; ++n) {
    float bv = P.bias[n * 16 + c];
#pragma unroll
    for (int ms = 0; ms < 2; ++ms) {
#pragma unroll
      for (int r = 0; r < 4; ++r) {
        int row = row0 + ms * 16 + q * 4 + r;
        if (row < P.N) P.Y[(size_t)row * 32 + n * 16 + c] = acc[ms][n][r] + bv;
      }
    }
  }
}
__global__ __launch_bounds__(256) void k_dual_postlin(PostSide A, PostSide B) {
  if ((int)blockIdx.x < A.nblk) postlin_body(A, blockIdx.x);
  else postlin_body(B, blockIdx.x - A.nblk);
}

extern "C" void kernel_launch(void* const* d_in, const int* in_sizes, int n_in,
                              void* d_out, int out_size, void* d_ws, size_t ws_size,
                              hipStream_t stream) {
  const float* x_user = (const float*)d_in[0];
  const float* x_item = (const float*)d_in[1];
  const int* ei_u2i = (const int*)d_in[2];
  const int* ei_i2u = (const int*)d_in[3];

  const int NU = in_sizes[0] / FDIM;
  const int NI = in_sizes[1] / FDIM;
  const int E = in_sizes[2] / 2;

  const int SH_I = 8, SH_U = 9;
  const int nbI = (NI + (1 << SH_I) - 1) >> SH_I;
  const int nbU = (NU + (1 << SH_U) - 1) >> SH_U;

  // ---- workspace ----
  u16* wsu = (u16*)d_ws;
  u16* h_u = wsu;   wsu += (size_t)NU * FDIM;
  u16* h_i = wsu;   wsu += (size_t)NI * FDIM;
  u16* x1_u = wsu;  wsu += (size_t)NU * FDIM;
  u16* x1_i = wsu;  wsu += (size_t)NI * FDIM;
  u16* msg_i = wsu; wsu += (size_t)NI * FDIM;
  u16* msg_u = wsu; wsu += (size_t)NU * FDIM;
  u16* wb = wsu;    wsu += 12 * 4096;
  int2* aux_i = (int2*)wsu;
  int2* aux_u = aux_i + (size_t)nbI * SLOT_S;
  int* wsi = (int*)(aux_u + (size_t)nbU * SLOT_S);
  int* off_i = wsi;    wsi += NI + 1;
  int* off_u = wsi;    wsi += NU + 1;
  int* boff_i = wsi;   wsi += nbI + 1;
  int* boff_u = wsi;   wsi += nbU + 1;
  int* gcurb_i = wsi;  wsi += 512;
  int* gcurb_u = wsi;  wsi += 512;
  int* csr_u2i = wsi;  wsi += E + 16;  // +16 pad for unclamped overread
  int* csr_i2u = wsi;  wsi += E + 16;

  const int* u2i_src = ei_u2i;
  const int* u2i_dst = ei_u2i + E;
  const int* i2u_src = ei_i2u;
  const int* i2u_dst = ei_i2u + E;

  const int gA = (E + PA_C - 1) / PA_C;
  const int tU = (NU + 127) / 128;
  const int tI = (NI + 127) / 128;
  const int blkU = (tU + TPB_G - 1) / TPB_G;
  const int blkI = (tI + TPB_G - 1) / TPB_G;
  const int gGI = (NI + 7) / 8;
  const int gGU = (NU + 7) / 8;

  // ---- weight conversion (skip folded: wroot + I) ----
  WTab tab;
  const int widx[12] = {4, 6, 8, 10, 11, 13, 14, 16, 17, 19, 20, 22};
  const int addI[12] = {0, 0, 0, 1, 0, 1, 0, 1, 0, 1, 0, 0};
  const int rows_[12] = {64, 64, 64, 64, 64, 64, 64, 64, 64, 64, 32, 32};
  for (int i = 0; i < 12; ++i) {
    tab.src[i] = (const float*)d_in[widx[i]];
    tab.dst[i] = wb + i * 4096;
    tab.rows[i] = rows_[i];
    tab.addI[i] = addI[i];
  }
  k_wconv<<<12, 256, 0, stream>>>(tab);
  k_init_gcurb<<<(nbI + nbU + 255) / 256, 256, 0, stream>>>(gcurb_i, nbI, gcurb_u, nbU,
                                                            csr_u2i + E, csr_i2u + E);

  // ---- pre linears (dual, pipelined): fp32 x -> bf16 h ----
  {
    GemmSide a{x_user, nullptr, wb + 0 * 4096, nullptr, (const float*)d_in[5],
               h_u, NU, 0, tU, blkU};
    GemmSide b{x_item, nullptr, wb + 1 * 4096, nullptr, (const float*)d_in[7],
               h_i, NI, 0, tI, blkI};
    k_dual_pre_gemm<<<blkU + blkI, 256, 0, stream>>>(a, b);
  }

  // ---- CSR build (slotted aux; no pre-count) ----
  {
    BinASide a{u2i_src, u2i_dst, SH_I, nbI, gcurb_i, aux_i};
    BinASide b{i2u_src, i2u_dst, SH_U, nbU, gcurb_u, aux_u};
    k_dual_binA<<<2 * gA, 256, 0, stream>>>(a, b, E, gA);
  }
  k_bscan2<<<1, 512, 0, stream>>>(gcurb_i, nbI, gcurb_u, nbU, boff_i, boff_u);
  {
    BinBSide a{aux_i, gcurb_i, boff_i, SH_I, NI, off_i, csr_u2i, nbI};
    BinBSide b{aux_u, gcurb_u, boff_u, SH_U, NU, off_u, csr_i2u, nbU};
    k_dual_binB<<<nbI + nbU, 256, 0, stream>>>(a, b);
  }

  // ---- layer 1: both gathers in one dispatch, both convs in one ----
  {
    GathSide a{(const u32*)h_u, off_i, csr_u2i, (u32*)msg_i, NI, gGI};
    GathSide b{(const u32*)h_i, off_u, csr_i2u, (u32*)msg_u, NU, gGU};
    k_dual_gather<<<gGI + gGU, 256, 0, stream>>>(a, b);
  }
  {
    GemmSide a{msg_i, h_i, wb + 2 * 4096, wb + 3 * 4096, (const float*)d_in[9],
               x1_i, NI, 1, tI, blkI};
    GemmSide b{msg_u, h_u, wb + 4 * 4096, wb + 5 * 4096, (const float*)d_in[12],
               x1_u, NU, 1, tU, blkU};
    k_dual_conv_gemm<<<blkI + blkU, 256, 0, stream>>>(a, b);
  }

  // ---- layer 2 (outputs overwrite h_i / h_u) ----
  {
    GathSide a{(const u32*)x1_u, off_i, csr_u2i, (u32*)msg_i, NI, gGI};
    GathSide b{(const u32*)x1_i, off_u, csr_i2u, (u32*)msg_u, NU, gGU};
    k_dual_gather<<<gGI + gGU, 256, 0, stream>>>(a, b);
  }
  {
    GemmSide a{msg_i, x1_i, wb + 6 * 4096, wb + 7 * 4096, (const float*)d_in[15],
               h_i, NI, 1, tI, blkI};
    GemmSide b{msg_u, x1_u, wb + 8 * 4096, wb + 9 * 4096, (const float*)d_in[18],
               h_u, NU, 1, tU, blkU};
    k_dual_conv_gemm<<<blkI + blkU, 256, 0, stream>>>(a, b);
  }

  // ---- post linears (dual) -> fp32 d_out = [out_u | out_i] ----
  {
    float* out = (float*)d_out;
    PostSide a{h_u, wb + 10 * 4096, (const float*)d_in[21], out, NU, (tU + 0)};
    PostSide b{h_i, wb + 11 * 4096, (const float*)d_in[23], out + (size_t)NU * 32, NI, tI};
    k_dual_postlin<<<tU + tI, 256, 0, stream>>>(a, b);
  }
}

// Round 8
// 396.923 us; speedup vs baseline: 1.5419x; 1.0162x over previous
//
#include <hip/hip_runtime.h>

// RGCN: hetero 2-layer GraphConv (mean aggr), MI355X.
// R12: (a) GEMM clamped loads -- R10/R11 gemm waves spent ~37k cy/tile
// regardless of TLP or tile-amortization => per-load serialization from
// `ok ? load : zf` cndmask chains. Now loads are unconditional with
// row clamped to N-1 (MFMA C-row m depends only on A-row m; garbage
// clamped rows only affect unstored C rows). (b) gather 8B-lane remap:
// wave = 4 dsts x 16 lanes (u32x2 row chunks), halving instrs/edge-visit
// (3 -> 2) and doubling bytes per row-load instruction.
// CSR build (R9), pipelined TPB_G=4 GEMM structure (R11) unchanged.

#define FDIM 64
typedef unsigned short u16;
typedef unsigned int u32;
typedef __bf16 bf16x8 __attribute__((ext_vector_type(8)));
typedef float f32x4 __attribute__((ext_vector_type(4)));
typedef float f32x2 __attribute__((ext_vector_type(2)));
typedef unsigned int u32x2 __attribute__((ext_vector_type(2)));

#define SLOT_S 3072
#define TPB_G 4

__device__ __forceinline__ u16 f2bf(float x) {  // RNE
  u32 b = __builtin_bit_cast(u32, x);
  b += 0x7FFFu + ((b >> 16) & 1u);
  return (u16)(b >> 16);
}
__device__ __forceinline__ float blo(u32 p) { return __builtin_bit_cast(float, p << 16); }
__device__ __forceinline__ float bhi(u32 p) { return __builtin_bit_cast(float, p & 0xffff0000u); }

// ---- weight conversion: 12 arrays fp32 -> bf16, optional +I (skip fold) ----
struct WTab {
  const float* src[12];
  u16* dst[12];
  int rows[12];
  int addI[12];
};
__global__ __launch_bounds__(256) void k_wconv(WTab p) {
  int b = blockIdx.x;
  const float* s = p.src[b];
  u16* d = p.dst[b];
  int n = p.rows[b] * 64;
  int addI = p.addI[b];
  for (int i = threadIdx.x; i < n; i += 256) {
    float v = s[i];
    if (addI && (i >> 6) == (i & 63)) v += 1.0f;
    d[i] = f2bf(v);
  }
}

// ---- init binA cursors to slot bases + zero csr pads ----
__global__ __launch_bounds__(256) void k_init_gcurb(int* __restrict__ gA, int nA,
                                                    int* __restrict__ gB, int nB,
                                                    int* __restrict__ padA,
                                                    int* __restrict__ padB) {
  int i = blockIdx.x * 256 + threadIdx.x;
  if (i < nA) gA[i] = i * SLOT_S;
  else if (i < nA + nB) gB[i - nA] = (i - nA) * SLOT_S;
  if (i < 16) { padA[i] = 0; padB[i] = 0; }
}

// ---- bucket scan (post-binA): counts = gcurb[b]-b*S, exclusive scan ----
__global__ __launch_bounds__(512) void k_bscan2(const int* __restrict__ gcA, int nbA,
                                                const int* __restrict__ gcB, int nbB,
                                                int* __restrict__ boffA,
                                                int* __restrict__ boffB) {
  __shared__ int sd[512];
  int t = threadIdx.x;
  for (int side = 0; side < 2; ++side) {
    const int* gc = side ? gcB : gcA;
    int nb = side ? nbB : nbA;
    int v = (t < nb) ? gc[t] - t * SLOT_S : 0;
    sd[t] = v; __syncthreads();
    int sum = v;
    for (int o = 1; o < 512; o <<= 1) {
      int x = (t >= o) ? sd[t - o] : 0;
      __syncthreads();
      sum += x; sd[t] = sum;
      __syncthreads();
    }
    int* bo = side ? boffB : boffA;
    if (t < nb) bo[t] = sum - v;
    if (t == nb - 1) bo[nb] = sum;
    __syncthreads();
  }
}

// ---- Pass A (dual): bin edges into per-bucket slot regions ----
#define PA_C 4096
struct BinASide {
  const int* src; const int* dst; int shift; int nb; int* gcurb; int2* aux;
};
__global__ __launch_bounds__(256) void k_dual_binA(BinASide A, BinASide B, int E, int gA) {
  int bid = blockIdx.x;
  const BinASide& P = (bid < gA) ? A : B;
  if (bid >= gA) bid -= gA;
  __shared__ int cnt[512];
  __shared__ int base[512];
  int t = threadIdx.x;
  int e0 = bid * PA_C;
  int n = min(PA_C, E - e0);
  int nb = P.nb, shift = P.shift;
  for (int b = t; b < nb; b += 256) cnt[b] = 0;
  __syncthreads();
  int ls[16], ld[16];
#pragma unroll
  for (int i = 0; i < 16; ++i) {
    int r = t + i * 256;
    if (r < n) {
      ls[i] = P.src[e0 + r];
      ld[i] = P.dst[e0 + r];
      atomicAdd(&cnt[ld[i] >> shift], 1);
    }
  }
  __syncthreads();
  for (int b = t; b < nb; b += 256) {
    int c = cnt[b];
    base[b] = c ? atomicAdd(&P.gcurb[b], c) : 0;
  }
  __syncthreads();
  for (int b = t; b < nb; b += 256) cnt[b] = 0;
  __syncthreads();
#pragma unroll
  for (int i = 0; i < 16; ++i) {
    int r = t + i * 256;
    if (r < n) {
      int b = ld[i] >> shift;
      int p = base[b] + atomicAdd(&cnt[b], 1);
      P.aux[p] = make_int2(ls[i], ld[i]);
    }
  }
}

// ---- Pass B (dual): per bucket -- LDS per-dst count + scan -> off[],
// then LDS-cursor scatter from slotted aux into compact csr ----
struct BinBSide {
  const int2* aux; const int* gcurb; const int* boff; int shift; int N;
  int* off; int* csr; int nblk;
};
__global__ __launch_bounds__(256) void k_dual_binB(BinBSide A, BinBSide B) {
  __shared__ int stage[4096];
  __shared__ int lcnt[512];
  __shared__ int sd[256];
  int b = blockIdx.x;
  const BinBSide& P = (b < A.nblk) ? A : B;
  if (b >= A.nblk) b -= A.nblk;
  int t = threadIdx.x;
  int d0 = b << P.shift;
  int d1 = min(d0 + (1 << P.shift), P.N);
  int nd = d1 - d0;
  size_t a0 = (size_t)b * SLOT_S;
  int r0 = P.boff[b];
  int RS = P.gcurb[b] - b * SLOT_S;
  for (int i = t; i < nd; i += 256) lcnt[i] = 0;
  __syncthreads();
  for (int i = t; i < RS; i += 256) {
    int2 p = P.aux[a0 + i];
    atomicAdd(&lcnt[p.y - d0], 1);
  }
  __syncthreads();
  // exclusive scan over nd (<=512) entries, 2 per thread
  int i0 = 2 * t, i1 = 2 * t + 1;
  int v0 = (i0 < nd) ? lcnt[i0] : 0;
  int v1 = (i1 < nd) ? lcnt[i1] : 0;
  int local = v0 + v1;
  sd[t] = local; __syncthreads();
  int sum = local;
  for (int o = 1; o < 256; o <<= 1) {
    int x = (t >= o) ? sd[t - o] : 0;
    __syncthreads();
    sum += x; sd[t] = sum;
    __syncthreads();
  }
  int run = sum - local;
  if (i0 < nd) { lcnt[i0] = run; P.off[d0 + i0] = r0 + run; }
  if (i1 < nd) { lcnt[i1] = run + v0; P.off[d0 + i1] = r0 + run + v0; }
  if (t == 0 && d1 == P.N) P.off[P.N] = r0 + RS;
  __syncthreads();
  if (RS <= 4096) {
    for (int i = t; i < RS; i += 256) {
      int2 p = P.aux[a0 + i];
      int pos = atomicAdd(&lcnt[p.y - d0], 1);
      stage[pos] = p.x;
    }
    __syncthreads();
    for (int i = t; i < RS; i += 256) P.csr[r0 + i] = stage[i];
  } else {
    for (int i = t; i < RS; i += 256) {
      int2 p = P.aux[a0 + i];
      int pos = atomicAdd(&lcnt[p.y - d0], 1);
      P.csr[r0 + pos] = p.x;
    }
  }
}

// ---- dual gather-mean: wave = 4 dsts; lane = (dst dd, u32x2 chunk c) ----
// R12: 8B row chunks per lane (16 lanes/dst). Full rounds unmasked (csr
// padded +16 zeros), 32-bit saddr addressing, pipelined idx prefetch.
struct GathSide {
  const u32* xs; const int* off; const int* csr; u32* msg; int N; int nblk;
};
__global__ __launch_bounds__(256) void k_dual_gather(GathSide A, GathSide B) {
  int bid = blockIdx.x;
  const GathSide& P = (bid < A.nblk) ? A : B;
  if (bid >= A.nblk) bid -= A.nblk;
  int lane = threadIdx.x & 63;
  int dd = lane >> 4, c = lane & 15;
  int d = bid * 16 + (int)(threadIdx.x >> 6) * 4 + dd;
  if (d >= P.N) return;
  int beg = P.off[d];
  int deg = P.off[d + 1] - beg;
  const char* xsb = (const char*)P.xs;
  const int* cp = P.csr + beg;
  u32 c8 = (u32)(c << 3);
  f32x2 s0 = {0.f, 0.f}, s1 = {0.f, 0.f};
  if (deg > 0) {
    int idx[8];
#pragma unroll
    for (int i = 0; i < 8; ++i) idx[i] = cp[i];  // overread <=7: pad-safe
    int j = 0;
    for (; j + 8 <= deg; j += 8) {  // full rounds, no mask
      u32x2 p[8];
#pragma unroll
      for (int i = 0; i < 8; ++i)
        p[i] = *(const u32x2*)(xsb + (size_t)((((u32)idx[i]) << 7) | c8));
#pragma unroll
      for (int i = 0; i < 8; ++i) idx[i] = cp[j + 8 + i];  // overread <=15: pad-safe
#pragma unroll
      for (int i = 0; i < 8; ++i) {
        f32x2 v0 = {blo(p[i][0]), bhi(p[i][0])};
        f32x2 v1 = {blo(p[i][1]), bhi(p[i][1])};
        s0 += v0; s1 += v1;
      }
    }
    if (j < deg) {  // single masked tail round (idx already loaded)
      u32x2 p[8];
#pragma unroll
      for (int i = 0; i < 8; ++i)
        p[i] = *(const u32x2*)(xsb + (size_t)((((u32)idx[i]) << 7) | c8));
#pragma unroll
      for (int i = 0; i < 8; ++i) {
        float m = (j + i < deg) ? 1.0f : 0.0f;
        f32x2 v0 = {blo(p[i][0]) * m, bhi(p[i][0]) * m};
        f32x2 v1 = {blo(p[i][1]) * m, bhi(p[i][1]) * m};
        s0 += v0; s1 += v1;
      }
    }
  }
  float sc = 1.0f / fmaxf((float)deg, 1.0f);
  u32x2 outv;
  outv[0] = (u32)f2bf(s0[0] * sc) | ((u32)f2bf(s0[1] * sc) << 16);
  outv[1] = (u32)f2bf(s1[0] * sc) | ((u32)f2bf(s1[1] * sc) << 16);
  *(u32x2*)((char*)P.msg + (((size_t)d) << 7) + c8) = outv;
}

// ---- pipelined MFMA GEMMs: Y[N,64](bf16) = act( A1@W1^T [+ A2@W2^T] + b )
// Block = TPB_G consecutive 128-row tiles; wave = 32 rows x 64 cols.
// W frags + bias in registers once per wave; A frags double-buffered.
// Loads are UNCONDITIONAL with row clamped to N-1 (no cndmask chains);
// garbage clamped rows only affect C rows >= N which are never stored.
struct GemmSide {
  const void* A1; const u16* A2; const u16* W1; const u16* W2;
  const float* bias; u16* Y; int N; int dorelu; int ntile; int nblk;
};

__device__ __forceinline__ void conv_body(const GemmSide& P, int bid) {
  const int t = threadIdx.x;
  const int w = t >> 6, lane = t & 63;
  const int c = lane & 15, q = lane >> 4;
  int t0 = bid * TPB_G;
  int t1 = min(t0 + TPB_G, P.ntile);

  bf16x8 wf[2][4][2];
#pragma unroll
  for (int hh = 0; hh < 2; ++hh)
#pragma unroll
    for (int n = 0; n < 4; ++n)
#pragma unroll
      for (int kc = 0; kc < 2; ++kc)
        wf[hh][n][kc] = *(const bf16x8*)((hh ? P.W2 : P.W1) + (n * 16 + c) * 64 + kc * 32 + q * 8);
  float bv[4];
#pragma unroll
  for (int n = 0; n < 4; ++n) bv[n] = P.bias[n * 16 + c];

  const u16* A1 = (const u16*)P.A1;
  const u16* A2 = P.A2;

  bf16x8 aX[2][2][2], aY[2][2][2];  // [hh][ms][kc]

  auto issue = [&](int tt, bf16x8 (&buf)[2][2][2]) {
#pragma unroll
    for (int ms = 0; ms < 2; ++ms) {
      int row = tt * 128 + w * 32 + ms * 16 + c;
      int lr = min(row, P.N - 1);
#pragma unroll
      for (int kc = 0; kc < 2; ++kc) {
        buf[0][ms][kc] = *(const bf16x8*)(A1 + (size_t)lr * 64 + kc * 32 + q * 8);
        buf[1][ms][kc] = *(const bf16x8*)(A2 + (size_t)lr * 64 + kc * 32 + q * 8);
      }
    }
  };
  auto work = [&](int tt, bf16x8 (&buf)[2][2][2]) {
    f32x4 acc[2][4];
#pragma unroll
    for (int ms = 0; ms < 2; ++ms)
#pragma unroll
      for (int n = 0; n < 4; ++n) acc[ms][n] = f32x4{0.f, 0.f, 0.f, 0.f};
#pragma unroll
    for (int hh = 0; hh < 2; ++hh)
#pragma unroll
      for (int n = 0; n < 4; ++n)
#pragma unroll
        for (int ms = 0; ms < 2; ++ms)
#pragma unroll
          for (int kc = 0; kc < 2; ++kc)
            acc[ms][n] = __builtin_amdgcn_mfma_f32_16x16x32_bf16(buf[hh][ms][kc], wf[hh][n][kc],
                                                                 acc[ms][n], 0, 0, 0);
    int row0 = tt * 128 + w * 32;
#pragma unroll
    for (int n = 0; n < 4; ++n) {
#pragma unroll
      for (int ms = 0; ms < 2; ++ms) {
#pragma unroll
        for (int r = 0; r < 4; ++r) {
          int row = row0 + ms * 16 + q * 4 + r;
          if (row < P.N) {
            float v = acc[ms][n][r] + bv[n];
            if (P.dorelu) v = fmaxf(v, 0.f);
            P.Y[(size_t)row * 64 + n * 16 + c] = f2bf(v);
          }
        }
      }
    }
  };

  int tt = t0;
  issue(tt, aX);
  for (; tt + 2 <= t1; tt += 2) {
    issue(tt + 1, aY);
    work(tt, aX);
    if (tt + 2 < t1) issue(tt + 2, aX);
    work(tt + 1, aY);
  }
  if (tt < t1) work(tt, aX);
}
__global__ __launch_bounds__(256) void k_dual_conv_gemm(GemmSide A, GemmSide B) {
  if ((int)blockIdx.x < A.nblk) conv_body(A, blockIdx.x);
  else conv_body(B, blockIdx.x - A.nblk);
}

__device__ __forceinline__ void pre_body(const GemmSide& P, int bid) {
  const int t = threadIdx.x;
  const int w = t >> 6, lane = t & 63;
  const int c = lane & 15, q = lane >> 4;
  int t0 = bid * TPB_G;
  int t1 = min(t0 + TPB_G, P.ntile);

  bf16x8 wf[4][2];
#pragma unroll
  for (int n = 0; n < 4; ++n)
#pragma unroll
    for (int kc = 0; kc < 2; ++kc)
      wf[n][kc] = *(const bf16x8*)(P.W1 + (n * 16 + c) * 64 + kc * 32 + q * 8);
  float bv[4];
#pragma unroll
  for (int n = 0; n < 4; ++n) bv[n] = P.bias[n * 16 + c];

  const float* A1 = (const float*)P.A1;

  f32x4 rX[2][2][2], rY[2][2][2];  // [ms][kc][half]

  auto issue = [&](int tt, f32x4 (&buf)[2][2][2]) {
#pragma unroll
    for (int ms = 0; ms < 2; ++ms) {
      int row = tt * 128 + w * 32 + ms * 16 + c;
      int lr = min(row, P.N - 1);
#pragma unroll
      for (int kc = 0; kc < 2; ++kc) {
        const float* Af = A1 + (size_t)lr * 64 + kc * 32 + q * 8;
        buf[ms][kc][0] = *(const f32x4*)Af;
        buf[ms][kc][1] = *(const f32x4*)(Af + 4);
      }
    }
  };
  auto work = [&](int tt, f32x4 (&buf)[2][2][2]) {
    f32x4 acc[2][4];
#pragma unroll
    for (int ms = 0; ms < 2; ++ms)
#pragma unroll
      for (int n = 0; n < 4; ++n) acc[ms][n] = f32x4{0.f, 0.f, 0.f, 0.f};
    bf16x8 afr[2][2];
#pragma unroll
    for (int ms = 0; ms < 2; ++ms)
#pragma unroll
      for (int kc = 0; kc < 2; ++kc) {
        bf16x8 v;
#pragma unroll
        for (int i = 0; i < 4; ++i) {
          v[i] = (__bf16)buf[ms][kc][0][i];
          v[4 + i] = (__bf16)buf[ms][kc][1][i];
        }
        afr[ms][kc] = v;
      }
#pragma unroll
    for (int n = 0; n < 4; ++n)
#pragma unroll
      for (int ms = 0; ms < 2; ++ms)
#pragma unroll
        for (int kc = 0; kc < 2; ++kc)
          acc[ms][n] = __builtin_amdgcn_mfma_f32_16x16x32_bf16(afr[ms][kc], wf[n][kc],
                                                               acc[ms][n], 0, 0, 0);
    int row0 = tt * 128 + w * 32;
#pragma unroll
    for (int n = 0; n < 4; ++n) {
#pragma unroll
      for (int ms = 0; ms < 2; ++ms) {
#pragma unroll
        for (int r = 0; r < 4; ++r) {
          int row = row0 + ms * 16 + q * 4 + r;
          if (row < P.N) P.Y[(size_t)row * 64 + n * 16 + c] = f2bf(acc[ms][n][r] + bv[n]);
        }
      }
    }
  };

  int tt = t0;
  issue(tt, rX);
  for (; tt + 2 <= t1; tt += 2) {
    issue(tt + 1, rY);
    work(tt, rX);
    if (tt + 2 < t1) issue(tt + 2, rX);
    work(tt + 1, rY);
  }
  if (tt < t1) work(tt, rX);
}
__global__ __launch_bounds__(256) void k_dual_pre_gemm(GemmSide A, GemmSide B) {
  if ((int)blockIdx.x < A.nblk) pre_body(A, blockIdx.x);
  else pre_body(B, blockIdx.x - A.nblk);
}

// ---- dual MFMA post linear: Y[N,32](fp32) = A(bf16) @ W[32,64]^T + bias ----
struct PostSide {
  const u16* A; const u16* W; const float* bias; float* Y; int N; int nblk;
};
__device__ __forceinline__ void postlin_body(const PostSide& P, int bid) {
  const int t = threadIdx.x;
  const int w = t >> 6, lane = t & 63;
  const int c = lane & 15, q = lane >> 4;
  const int row0 = bid * 128 + w * 32;

  f32x4 acc[2][2];
#pragma unroll
  for (int ms = 0; ms < 2; ++ms)
#pragma unroll
    for (int n = 0; n < 2; ++n) acc[ms][n] = f32x4{0.f, 0.f, 0.f, 0.f};

  bf16x8 bfr[2][2];
#pragma unroll
  for (int n = 0; n < 2; ++n)
#pragma unroll
    for (int kc = 0; kc < 2; ++kc)
      bfr[n][kc] = *(const bf16x8*)(P.W + (n * 16 + c) * 64 + kc * 32 + q * 8);
  bf16x8 afr[2][2];
#pragma unroll
  for (int ms = 0; ms < 2; ++ms) {
    int row = row0 + ms * 16 + c;
    int lr = min(row, P.N - 1);
#pragma unroll
    for (int kc = 0; kc < 2; ++kc)
      afr[ms][kc] = *(const bf16x8*)(P.A + (size_t)lr * 64 + kc * 32 + q * 8);
  }
#pragma unroll
  for (int n = 0; n < 2; ++n)
#pragma unroll
    for (int ms = 0; ms < 2; ++ms)
#pragma unroll
      for (int kc = 0; kc < 2; ++kc)
        acc[ms][n] = __builtin_amdgcn_mfma_f32_16x16x32_bf16(afr[ms][kc], bfr[n][kc],
                                                             acc[ms][n], 0, 0, 0);
#pragma unroll
  for (int n = 0; n < 2; ++n) {
    float bv = P.bias[n * 16 + c];
#pragma unroll
    for (int ms = 0; ms < 2; ++ms) {
#pragma unroll
      for (int r = 0; r < 4; ++r) {
        int row = row0 + ms * 16 + q * 4 + r;
        if (row < P.N) P.Y[(size_t)row * 32 + n * 16 + c] = acc[ms][n][r] + bv;
      }
    }
  }
}
__global__ __launch_bounds__(256) void k_dual_postlin(PostSide A, PostSide B) {
  if ((int)blockIdx.x < A.nblk) postlin_body(A, blockIdx.x);
  else postlin_body(B, blockIdx.x - A.nblk);
}

extern "C" void kernel_launch(void* const* d_in, const int* in_sizes, int n_in,
                              void* d_out, int out_size, void* d_ws, size_t ws_size,
                              hipStream_t stream) {
  const float* x_user = (const float*)d_in[0];
  const float* x_item = (const float*)d_in[1];
  const int* ei_u2i = (const int*)d_in[2];
  const int* ei_i2u = (const int*)d_in[3];

  const int NU = in_sizes[0] / FDIM;
  const int NI = in_sizes[1] / FDIM;
  const int E = in_sizes[2] / 2;

  const int SH_I = 8, SH_U = 9;
  const int nbI = (NI + (1 << SH_I) - 1) >> SH_I;
  const int nbU = (NU + (1 << SH_U) - 1) >> SH_U;

  // ---- workspace ----
  u16* wsu = (u16*)d_ws;
  u16* h_u = wsu;   wsu += (size_t)NU * FDIM;
  u16* h_i = wsu;   wsu += (size_t)NI * FDIM;
  u16* x1_u = wsu;  wsu += (size_t)NU * FDIM;
  u16* x1_i = wsu;  wsu += (size_t)NI * FDIM;
  u16* msg_i = wsu; wsu += (size_t)NI * FDIM;
  u16* msg_u = wsu; wsu += (size_t)NU * FDIM;
  u16* wb = wsu;    wsu += 12 * 4096;
  int2* aux_i = (int2*)wsu;
  int2* aux_u = aux_i + (size_t)nbI * SLOT_S;
  int* wsi = (int*)(aux_u + (size_t)nbU * SLOT_S);
  int* off_i = wsi;    wsi += NI + 1;
  int* off_u = wsi;    wsi += NU + 1;
  int* boff_i = wsi;   wsi += nbI + 1;
  int* boff_u = wsi;   wsi += nbU + 1;
  int* gcurb_i = wsi;  wsi += 512;
  int* gcurb_u = wsi;  wsi += 512;
  int* csr_u2i = wsi;  wsi += E + 16;  // +16 pad for unclamped overread
  int* csr_i2u = wsi;  wsi += E + 16;

  const int* u2i_src = ei_u2i;
  const int* u2i_dst = ei_u2i + E;
  const int* i2u_src = ei_i2u;
  const int* i2u_dst = ei_i2u + E;

  const int gA = (E + PA_C - 1) / PA_C;
  const int tU = (NU + 127) / 128;
  const int tI = (NI + 127) / 128;
  const int blkU = (tU + TPB_G - 1) / TPB_G;
  const int blkI = (tI + TPB_G - 1) / TPB_G;
  const int gGI = (NI + 15) / 16;
  const int gGU = (NU + 15) / 16;

  // ---- weight conversion (skip folded: wroot + I) ----
  WTab tab;
  const int widx[12] = {4, 6, 8, 10, 11, 13, 14, 16, 17, 19, 20, 22};
  const int addI[12] = {0, 0, 0, 1, 0, 1, 0, 1, 0, 1, 0, 0};
  const int rows_[12] = {64, 64, 64, 64, 64, 64, 64, 64, 64, 64, 32, 32};
  for (int i = 0; i < 12; ++i) {
    tab.src[i] = (const float*)d_in[widx[i]];
    tab.dst[i] = wb + i * 4096;
    tab.rows[i] = rows_[i];
    tab.addI[i] = addI[i];
  }
  k_wconv<<<12, 256, 0, stream>>>(tab);
  k_init_gcurb<<<(nbI + nbU + 255) / 256, 256, 0, stream>>>(gcurb_i, nbI, gcurb_u, nbU,
                                                            csr_u2i + E, csr_i2u + E);

  // ---- pre linears (dual, pipelined): fp32 x -> bf16 h ----
  {
    GemmSide a{x_user, nullptr, wb + 0 * 4096, nullptr, (const float*)d_in[5],
               h_u, NU, 0, tU, blkU};
    GemmSide b{x_item, nullptr, wb + 1 * 4096, nullptr, (const float*)d_in[7],
               h_i, NI, 0, tI, blkI};
    k_dual_pre_gemm<<<blkU + blkI, 256, 0, stream>>>(a, b);
  }

  // ---- CSR build (slotted aux; no pre-count) ----
  {
    BinASide a{u2i_src, u2i_dst, SH_I, nbI, gcurb_i, aux_i};
    BinASide b{i2u_src, i2u_dst, SH_U, nbU, gcurb_u, aux_u};
    k_dual_binA<<<2 * gA, 256, 0, stream>>>(a, b, E, gA);
  }
  k_bscan2<<<1, 512, 0, stream>>>(gcurb_i, nbI, gcurb_u, nbU, boff_i, boff_u);
  {
    BinBSide a{aux_i, gcurb_i, boff_i, SH_I, NI, off_i, csr_u2i, nbI};
    BinBSide b{aux_u, gcurb_u, boff_u, SH_U, NU, off_u, csr_i2u, nbU};
    k_dual_binB<<<nbI + nbU, 256, 0, stream>>>(a, b);
  }

  // ---- layer 1: both gathers in one dispatch, both convs in one ----
  {
    GathSide a{(const u32*)h_u, off_i, csr_u2i, (u32*)msg_i, NI, gGI};
    GathSide b{(const u32*)h_i, off_u, csr_i2u, (u32*)msg_u, NU, gGU};
    k_dual_gather<<<gGI + gGU, 256, 0, stream>>>(a, b);
  }
  {
    GemmSide a{msg_i, h_i, wb + 2 * 4096, wb + 3 * 4096, (const float*)d_in[9],
               x1_i, NI, 1, tI, blkI};
    GemmSide b{msg_u, h_u, wb + 4 * 4096, wb + 5 * 4096, (const float*)d_in[12],
               x1_u, NU, 1, tU, blkU};
    k_dual_conv_gemm<<<blkI + blkU, 256, 0, stream>>>(a, b);
  }

  // ---- layer 2 (outputs overwrite h_i / h_u) ----
  {
    GathSide a{(const u32*)x1_u, off_i, csr_u2i, (u32*)msg_i, NI, gGI};
    GathSide b{(const u32*)x1_i, off_u, csr_i2u, (u32*)msg_u, NU, gGU};
    k_dual_gather<<<gGI + gGU, 256, 0, stream>>>(a, b);
  }
  {
    GemmSide a{msg_i, x1_i, wb + 6 * 4096, wb + 7 * 4096, (const float*)d_in[15],
               h_i, NI, 1, tI, blkI};
    GemmSide b{msg_u, x1_u, wb + 8 * 4096, wb + 9 * 4096, (const float*)d_in[18],
               h_u, NU, 1, tU, blkU};
    k_dual_conv_gemm<<<blkI + blkU, 256, 0, stream>>>(a, b);
  }

  // ---- post linears (dual) -> fp32 d_out = [out_u | out_i] ----
  {
    float* out = (float*)d_out;
    PostSide a{h_u, wb + 10 * 4096, (const float*)d_in[21], out, NU, tU};
    PostSide b{h_i, wb + 11 * 4096, (const float*)d_in[23], out + (size_t)NU * 32, NI, tI};
    k_dual_postlin<<<tU + tI, 256, 0, stream>>>(a, b);
  }
}